// Round 1
// baseline (371.610 us; speedup 1.0000x reference)
//
#include <hip/hip_runtime.h>
#include <hip/hip_bf16.h>
#include <math.h>

// Problem constants
#define NB 16
#define NLC 1024
#define NLQ 128
#define ND 512
#define NEGV (-1.0e10f)

// ---------------------------------------------------------------------------
// Kernel 1: s_c[b,i] = dot(C[b,i,:], w1);  s_q[b,j] = dot(Q[b,j,:], w2)
// One wave (64 threads) per row.
__global__ __launch_bounds__(64) void k_scsq(const float* __restrict__ C,
                                             const float* __restrict__ Q,
                                             const float* __restrict__ w,
                                             float* __restrict__ sc,
                                             float* __restrict__ sq) {
    int blk = blockIdx.x;
    int lane = threadIdx.x;
    float acc = 0.f;
    if (blk < NB * NLC) {
        const float* row = C + (size_t)blk * ND;
        const float* w1 = w;
#pragma unroll
        for (int t = 0; t < ND / 64; ++t) {
            int d = lane + t * 64;
            acc += row[d] * w1[d];
        }
    } else {
        int idx = blk - NB * NLC;
        const float* row = Q + (size_t)idx * ND;
        const float* w2 = w + ND;
#pragma unroll
        for (int t = 0; t < ND / 64; ++t) {
            int d = lane + t * 64;
            acc += row[d] * w2[d];
        }
    }
#pragma unroll
    for (int off = 32; off >= 1; off >>= 1) acc += __shfl_xor(acc, off, 64);
    if (lane == 0) {
        if (blk < NB * NLC) sc[blk] = acc;
        else sq[blk - NB * NLC] = acc;
    }
}

// ---------------------------------------------------------------------------
// Kernel 2: S[b,i,j] = sc[b,i] + sq[b,j] + sum_d C[b,i,d]*w3[d]*Q[b,j,d]
// Tiled NT GEMM: BM=64 (i), BN=128 (all j), BK=32. 256 threads.
__global__ __launch_bounds__(256) void k_S(const float* __restrict__ C,
                                           const float* __restrict__ Q,
                                           const float* __restrict__ w,
                                           const float* __restrict__ sc,
                                           const float* __restrict__ sq,
                                           float* __restrict__ S) {
    constexpr int BM = 64, BK = 32;
    __shared__ float As[BM][BK + 1];
    __shared__ float Bs[NLQ][BK + 1];
    int b = blockIdx.y, i0 = blockIdx.x * BM;
    int tid = threadIdx.x;
    int tx = tid & 15, ty = tid >> 4;
    const float* w3 = w + 2 * ND;
    const float* Cb = C + ((size_t)b * NLC + i0) * ND;
    const float* Qb = Q + (size_t)b * NLQ * ND;

    float acc[4][8];
#pragma unroll
    for (int r = 0; r < 4; ++r)
#pragma unroll
        for (int c = 0; c < 8; ++c) acc[r][c] = 0.f;

    for (int k0 = 0; k0 < ND; k0 += BK) {
        // As: 64x32 floats = 512 float4, 2 per thread
#pragma unroll
        for (int t = 0; t < 2; ++t) {
            int task = tid + t * 256;
            int r = task >> 3;
            int c4 = (task & 7) << 2;
            float4 v = *(const float4*)&Cb[(size_t)r * ND + k0 + c4];
            float4 wv = *(const float4*)&w3[k0 + c4];
            As[r][c4 + 0] = v.x * wv.x;
            As[r][c4 + 1] = v.y * wv.y;
            As[r][c4 + 2] = v.z * wv.z;
            As[r][c4 + 3] = v.w * wv.w;
        }
        // Bs: 128x32 floats = 1024 float4, 4 per thread
#pragma unroll
        for (int t = 0; t < 4; ++t) {
            int task = tid + t * 256;
            int r = task >> 3;
            int c4 = (task & 7) << 2;
            float4 v = *(const float4*)&Qb[(size_t)r * ND + k0 + c4];
            Bs[r][c4 + 0] = v.x;
            Bs[r][c4 + 1] = v.y;
            Bs[r][c4 + 2] = v.z;
            Bs[r][c4 + 3] = v.w;
        }
        __syncthreads();
#pragma unroll
        for (int k = 0; k < BK; ++k) {
            float a[4], bb[8];
#pragma unroll
            for (int r = 0; r < 4; ++r) a[r] = As[ty * 4 + r][k];
#pragma unroll
            for (int c = 0; c < 4; ++c) bb[c] = Bs[tx * 4 + c][k];
#pragma unroll
            for (int c = 0; c < 4; ++c) bb[4 + c] = Bs[64 + tx * 4 + c][k];
#pragma unroll
            for (int r = 0; r < 4; ++r)
#pragma unroll
                for (int c = 0; c < 8; ++c) acc[r][c] += a[r] * bb[c];
        }
        __syncthreads();
    }
    const float* scb = sc + b * NLC + i0;
    const float* sqb = sq + b * NLQ;
    float* Sb = S + ((size_t)b * NLC + i0) * NLQ;
#pragma unroll
    for (int r = 0; r < 4; ++r) {
        int i = ty * 4 + r;
        float sci = scb[i];
        float4 o0, o1;
        o0.x = acc[r][0] + sci + sqb[tx * 4 + 0];
        o0.y = acc[r][1] + sci + sqb[tx * 4 + 1];
        o0.z = acc[r][2] + sci + sqb[tx * 4 + 2];
        o0.w = acc[r][3] + sci + sqb[tx * 4 + 3];
        o1.x = acc[r][4] + sci + sqb[64 + tx * 4 + 0];
        o1.y = acc[r][5] + sci + sqb[64 + tx * 4 + 1];
        o1.z = acc[r][6] + sci + sqb[64 + tx * 4 + 2];
        o1.w = acc[r][7] + sci + sqb[64 + tx * 4 + 3];
        *(float4*)&Sb[(size_t)i * NLQ + tx * 4] = o0;
        *(float4*)&Sb[(size_t)i * NLQ + 64 + tx * 4] = o1;
    }
}

// ---------------------------------------------------------------------------
// Kernel 3: row softmax stats (axis j) with Qmask. One wave per row (b,i).
__global__ __launch_bounds__(64) void k_rowstats(const float* __restrict__ S,
                                                 const int* __restrict__ Qmask,
                                                 float* __restrict__ rowmax,
                                                 float* __restrict__ rowsuminv) {
    int blk = blockIdx.x;      // b*NLC + i
    int b = blk >> 10;         // NLC = 1024
    int lane = threadIdx.x;
    const float* row = S + (size_t)blk * NLQ;
    const int* qm = Qmask + b * NLQ;
    float v0 = qm[lane] ? NEGV : row[lane];
    float v1 = qm[lane + 64] ? NEGV : row[lane + 64];
    float m = fmaxf(v0, v1);
#pragma unroll
    for (int off = 32; off >= 1; off >>= 1) m = fmaxf(m, __shfl_xor(m, off, 64));
    float s = expf(v0 - m) + expf(v1 - m);
#pragma unroll
    for (int off = 32; off >= 1; off >>= 1) s += __shfl_xor(s, off, 64);
    if (lane == 0) {
        rowmax[blk] = m;
        rowsuminv[blk] = 1.0f / s;
    }
}

// ---------------------------------------------------------------------------
// Kernel 4: column softmax partials (axis i) with Cmask. Block = (part,b),
// 128 threads (one per j), online max/sum over 128 rows.
__global__ __launch_bounds__(128) void k_colpart(const float* __restrict__ S,
                                                 const int* __restrict__ Cmask,
                                                 float* __restrict__ pm,
                                                 float* __restrict__ ps) {
    int b = blockIdx.y, part = blockIdx.x, j = threadIdx.x;
    const float* Sb = S + (size_t)b * NLC * NLQ;
    const int* cmb = Cmask + b * NLC;
    float m = -INFINITY, s = 0.f;
    int ibase = part * 128;
    for (int t = 0; t < 128; ++t) {
        int i = ibase + t;
        float v = cmb[i] ? NEGV : Sb[(size_t)i * NLQ + j];
        float mn = fmaxf(m, v);
        s = s * expf(m - mn) + expf(v - mn);
        m = mn;
    }
    pm[(b * 8 + part) * NLQ + j] = m;
    ps[(b * 8 + part) * NLQ + j] = s;
}

// Kernel 5: combine the 8 partials per (b,j).
__global__ __launch_bounds__(128) void k_colred(const float* __restrict__ pm,
                                                const float* __restrict__ ps,
                                                float* __restrict__ colmax,
                                                float* __restrict__ colsuminv) {
    int b = blockIdx.x, j = threadIdx.x;
    float M = -INFINITY;
#pragma unroll
    for (int p = 0; p < 8; ++p) M = fmaxf(M, pm[(b * 8 + p) * NLQ + j]);
    float s = 0.f;
#pragma unroll
    for (int p = 0; p < 8; ++p) s += ps[(b * 8 + p) * NLQ + j] * expf(pm[(b * 8 + p) * NLQ + j] - M);
    colmax[b * NLQ + j] = M;
    colsuminv[b * NLQ + j] = 1.0f / s;
}

// ---------------------------------------------------------------------------
// Kernel 6: S2tC[b,j,d] = sum_i P2[b,i,j]*C[b,i,d],
// P2 computed on the fly from S + col stats. Tile: 128(j) x 64(d), BK=16 (i).
__global__ __launch_bounds__(256) void k_S2tC(const float* __restrict__ S,
                                              const float* __restrict__ C,
                                              const int* __restrict__ Cmask,
                                              const float* __restrict__ colmax,
                                              const float* __restrict__ colsuminv,
                                              float* __restrict__ S2tC) {
    constexpr int BK = 16;
    __shared__ float Ps[BK][NLQ];
    __shared__ float Cs[BK][64 + 4];
    int b = blockIdx.y, d0 = blockIdx.x * 64;
    int tid = threadIdx.x, tx = tid & 15, ty = tid >> 4;
    const float* Sb = S + (size_t)b * NLC * NLQ;
    const float* Cb = C + (size_t)b * NLC * ND;
    const int* cmb = Cmask + b * NLC;
    const float* cm = colmax + b * NLQ;
    const float* csi = colsuminv + b * NLQ;

    float acc[8][4];
#pragma unroll
    for (int r = 0; r < 8; ++r)
#pragma unroll
        for (int c = 0; c < 4; ++c) acc[r][c] = 0.f;

    for (int i0 = 0; i0 < NLC; i0 += BK) {
        // Ps: 16x128 = 2048 scalars, 8 per thread, coalesced over j
#pragma unroll
        for (int t = 0; t < 8; ++t) {
            int task = tid + t * 256;
            int k = task >> 7;
            int j = task & 127;
            float v = cmb[i0 + k] ? NEGV : Sb[(size_t)(i0 + k) * NLQ + j];
            Ps[k][j] = expf(v - cm[j]) * csi[j];
        }
        // Cs: 16x64 = 256 float4, 1 per thread
        {
            int k = tid >> 4;
            int c4 = (tid & 15) << 2;
            float4 v = *(const float4*)&Cb[(size_t)(i0 + k) * ND + d0 + c4];
            Cs[k][c4 + 0] = v.x;
            Cs[k][c4 + 1] = v.y;
            Cs[k][c4 + 2] = v.z;
            Cs[k][c4 + 3] = v.w;
        }
        __syncthreads();
#pragma unroll
        for (int k = 0; k < BK; ++k) {
            float a[8], bb[4];
#pragma unroll
            for (int r = 0; r < 8; ++r) a[r] = Ps[k][ty * 8 + r];
#pragma unroll
            for (int c = 0; c < 4; ++c) bb[c] = Cs[k][tx * 4 + c];
#pragma unroll
            for (int r = 0; r < 8; ++r)
#pragma unroll
                for (int c = 0; c < 4; ++c) acc[r][c] += a[r] * bb[c];
        }
        __syncthreads();
    }
    float* Ob = S2tC + (size_t)b * NLQ * ND;
#pragma unroll
    for (int r = 0; r < 8; ++r) {
        int j = ty * 8 + r;
        float4 o;
        o.x = acc[r][0]; o.y = acc[r][1]; o.z = acc[r][2]; o.w = acc[r][3];
        *(float4*)&Ob[(size_t)j * ND + d0 + tx * 4] = o;
    }
}

// ---------------------------------------------------------------------------
// Kernel 7: A = P1 @ Q ; Bv = P1 @ S2tC ; out = [C, A, C*A, C*Bv]
// Tile 64(i) x 64(d), K=128 (j) in BK=32 chunks. P1 from S + row stats.
__global__ __launch_bounds__(256) void k_out(const float* __restrict__ S,
                                             const float* __restrict__ Q,
                                             const float* __restrict__ S2tC,
                                             const float* __restrict__ C,
                                             const int* __restrict__ Qmask,
                                             const float* __restrict__ rowmax,
                                             const float* __restrict__ rowsuminv,
                                             float* __restrict__ Out) {
    constexpr int BK = 32;
    __shared__ float Ps[64][BK + 1];
    __shared__ float Qs[BK][64 + 4];
    __shared__ float Vs[BK][64 + 4];
    int b = blockIdx.z, i0 = blockIdx.y * 64, d0 = blockIdx.x * 64;
    int tid = threadIdx.x, tx = tid & 15, ty = tid >> 4;
    const float* Sb = S + ((size_t)b * NLC + i0) * NLQ;
    const float* Qb = Q + (size_t)b * NLQ * ND;
    const float* Vb = S2tC + (size_t)b * NLQ * ND;
    const int* qm = Qmask + b * NLQ;
    const float* rm = rowmax + b * NLC + i0;
    const float* rsi = rowsuminv + b * NLC + i0;

    float accA[4][4], accB[4][4];
#pragma unroll
    for (int r = 0; r < 4; ++r)
#pragma unroll
        for (int c = 0; c < 4; ++c) { accA[r][c] = 0.f; accB[r][c] = 0.f; }

    for (int k0 = 0; k0 < NLQ; k0 += BK) {
        // Ps: 64x32 = 512 float4, 2 per thread, exp applied on load
#pragma unroll
        for (int t = 0; t < 2; ++t) {
            int task = tid + t * 256;
            int r = task >> 3;
            int c4 = (task & 7) << 2;
            float4 v = *(const float4*)&Sb[(size_t)r * NLQ + k0 + c4];
            float m = rm[r], si = rsi[r];
            int j = k0 + c4;
            Ps[r][c4 + 0] = qm[j + 0] ? 0.f : expf(v.x - m) * si;
            Ps[r][c4 + 1] = qm[j + 1] ? 0.f : expf(v.y - m) * si;
            Ps[r][c4 + 2] = qm[j + 2] ? 0.f : expf(v.z - m) * si;
            Ps[r][c4 + 3] = qm[j + 3] ? 0.f : expf(v.w - m) * si;
        }
        // Qs, Vs: 32x64 = 512 float4 each, 2 per thread each
#pragma unroll
        for (int t = 0; t < 2; ++t) {
            int task = tid + t * 256;
            int k = task >> 4;
            int c4 = (task & 15) << 2;
            float4 v = *(const float4*)&Qb[(size_t)(k0 + k) * ND + d0 + c4];
            Qs[k][c4 + 0] = v.x; Qs[k][c4 + 1] = v.y; Qs[k][c4 + 2] = v.z; Qs[k][c4 + 3] = v.w;
            float4 u = *(const float4*)&Vb[(size_t)(k0 + k) * ND + d0 + c4];
            Vs[k][c4 + 0] = u.x; Vs[k][c4 + 1] = u.y; Vs[k][c4 + 2] = u.z; Vs[k][c4 + 3] = u.w;
        }
        __syncthreads();
#pragma unroll
        for (int k = 0; k < BK; ++k) {
            float a[4], q4[4], v4[4];
#pragma unroll
            for (int r = 0; r < 4; ++r) a[r] = Ps[ty * 4 + r][k];
#pragma unroll
            for (int c = 0; c < 4; ++c) { q4[c] = Qs[k][tx * 4 + c]; v4[c] = Vs[k][tx * 4 + c]; }
#pragma unroll
            for (int r = 0; r < 4; ++r)
#pragma unroll
                for (int c = 0; c < 4; ++c) {
                    accA[r][c] += a[r] * q4[c];
                    accB[r][c] += a[r] * v4[c];
                }
        }
        __syncthreads();
    }

    // Epilogue: out = [C, A, C*A, C*Bv]
#pragma unroll
    for (int r = 0; r < 4; ++r) {
        int i = i0 + ty * 4 + r;
        float4 cv = *(const float4*)&C[((size_t)b * NLC + i) * ND + d0 + tx * 4];
        float* orow = Out + ((size_t)b * NLC + i) * (4 * ND);
        float4 av, bv, ca, cb;
        av.x = accA[r][0]; av.y = accA[r][1]; av.z = accA[r][2]; av.w = accA[r][3];
        bv.x = accB[r][0]; bv.y = accB[r][1]; bv.z = accB[r][2]; bv.w = accB[r][3];
        ca.x = cv.x * av.x; ca.y = cv.y * av.y; ca.z = cv.z * av.z; ca.w = cv.w * av.w;
        cb.x = cv.x * bv.x; cb.y = cv.y * bv.y; cb.z = cv.z * bv.z; cb.w = cv.w * bv.w;
        *(float4*)&orow[d0 + tx * 4] = cv;
        *(float4*)&orow[ND + d0 + tx * 4] = av;
        *(float4*)&orow[2 * ND + d0 + tx * 4] = ca;
        *(float4*)&orow[3 * ND + d0 + tx * 4] = cb;
    }
}

// ---------------------------------------------------------------------------
extern "C" void kernel_launch(void* const* d_in, const int* in_sizes, int n_in,
                              void* d_out, int out_size, void* d_ws, size_t ws_size,
                              hipStream_t stream) {
    const float* C = (const float*)d_in[0];
    const float* Q = (const float*)d_in[1];
    const int* Cmask = (const int*)d_in[2];
    const int* Qmask = (const int*)d_in[3];
    const float* w = (const float*)d_in[4];
    float* out = (float*)d_out;

    float* ws = (float*)d_ws;
    float* sc = ws;                          // 16384
    float* sq = sc + NB * NLC;               // 2048
    float* S = sq + NB * NLQ;                // 2097152
    float* rowmax = S + (size_t)NB * NLC * NLQ;   // 16384
    float* rowsuminv = rowmax + NB * NLC;    // 16384
    float* pm = rowsuminv + NB * NLC;        // 16384
    float* ps = pm + NB * 8 * NLQ;           // 16384
    float* colmax = ps + NB * 8 * NLQ;       // 2048
    float* colsuminv = colmax + NB * NLQ;    // 2048
    float* S2tC = colsuminv + NB * NLQ;      // 1048576

    k_scsq<<<dim3(NB * NLC + NB * NLQ), dim3(64), 0, stream>>>(C, Q, w, sc, sq);
    k_S<<<dim3(NLC / 64, NB), dim3(256), 0, stream>>>(C, Q, w, sc, sq, S);
    k_rowstats<<<dim3(NB * NLC), dim3(64), 0, stream>>>(S, Qmask, rowmax, rowsuminv);
    k_colpart<<<dim3(8, NB), dim3(128), 0, stream>>>(S, Cmask, pm, ps);
    k_colred<<<dim3(NB), dim3(128), 0, stream>>>(pm, ps, colmax, colsuminv);
    k_S2tC<<<dim3(ND / 64, NB), dim3(256), 0, stream>>>(S, C, Cmask, colmax, colsuminv, S2tC);
    k_out<<<dim3(ND / 64, NLC / 64, NB), dim3(256), 0, stream>>>(S, Q, S2tC, C, Qmask, rowmax, rowsuminv, out);
}

// Round 2
// 193.101 us; speedup vs baseline: 1.9244x; 1.9244x over previous
//
#include <hip/hip_runtime.h>
#include <hip/hip_bf16.h>
#include <math.h>

// Problem constants
#define NB 16
#define NLC 1024
#define NLQ 128
#define ND 512
#define NEGV (-1.0e10f)
#define KCH 8      // K-split chunks for S2tC (each 128 rows of i)
#define CPARTS 32  // column-softmax partial chunks (each 32 rows of i)

// ---------------------------------------------------------------------------
// Kernel 1: s_c[b,i] = dot(C[b,i,:], w1);  s_q[b,j] = dot(Q[b,j,:], w2)
__global__ __launch_bounds__(64) void k_scsq(const float* __restrict__ C,
                                             const float* __restrict__ Q,
                                             const float* __restrict__ w,
                                             float* __restrict__ sc,
                                             float* __restrict__ sq) {
    int blk = blockIdx.x;
    int lane = threadIdx.x;
    float acc = 0.f;
    if (blk < NB * NLC) {
        const float* row = C + (size_t)blk * ND;
        const float* w1 = w;
#pragma unroll
        for (int t = 0; t < ND / 64; ++t) {
            int d = lane + t * 64;
            acc += row[d] * w1[d];
        }
    } else {
        int idx = blk - NB * NLC;
        const float* row = Q + (size_t)idx * ND;
        const float* w2 = w + ND;
#pragma unroll
        for (int t = 0; t < ND / 64; ++t) {
            int d = lane + t * 64;
            acc += row[d] * w2[d];
        }
    }
#pragma unroll
    for (int off = 32; off >= 1; off >>= 1) acc += __shfl_xor(acc, off, 64);
    if (lane == 0) {
        if (blk < NB * NLC) sc[blk] = acc;
        else sq[blk - NB * NLC] = acc;
    }
}

// ---------------------------------------------------------------------------
// Kernel 2: S[b,i,j] = sc[b,i] + sq[b,j] + sum_d C[b,i,d]*w3[d]*Q[b,j,d]
// Fused epilogue: row-softmax stats (axis j, Qmask) via 16-lane shfl reduce.
__global__ __launch_bounds__(256) void k_S(const float* __restrict__ C,
                                           const float* __restrict__ Q,
                                           const float* __restrict__ w,
                                           const float* __restrict__ sc,
                                           const float* __restrict__ sq,
                                           const int* __restrict__ Qmask,
                                           float* __restrict__ S,
                                           float* __restrict__ rowmax,
                                           float* __restrict__ rowsuminv) {
    constexpr int BM = 64, BK = 32;
    __shared__ float As[BM][BK + 1];
    __shared__ float Bs[NLQ][BK + 1];
    int b = blockIdx.y, i0 = blockIdx.x * BM;
    int tid = threadIdx.x;
    int tx = tid & 15, ty = tid >> 4;
    const float* w3 = w + 2 * ND;
    const float* Cb = C + ((size_t)b * NLC + i0) * ND;
    const float* Qb = Q + (size_t)b * NLQ * ND;
    const int* qm = Qmask + b * NLQ;

    float acc[4][8];
#pragma unroll
    for (int r = 0; r < 4; ++r)
#pragma unroll
        for (int c = 0; c < 8; ++c) acc[r][c] = 0.f;

    for (int k0 = 0; k0 < ND; k0 += BK) {
#pragma unroll
        for (int t = 0; t < 2; ++t) {
            int task = tid + t * 256;
            int r = task >> 3;
            int c4 = (task & 7) << 2;
            float4 v = *(const float4*)&Cb[(size_t)r * ND + k0 + c4];
            float4 wv = *(const float4*)&w3[k0 + c4];
            As[r][c4 + 0] = v.x * wv.x;
            As[r][c4 + 1] = v.y * wv.y;
            As[r][c4 + 2] = v.z * wv.z;
            As[r][c4 + 3] = v.w * wv.w;
        }
#pragma unroll
        for (int t = 0; t < 4; ++t) {
            int task = tid + t * 256;
            int r = task >> 3;
            int c4 = (task & 7) << 2;
            float4 v = *(const float4*)&Qb[(size_t)r * ND + k0 + c4];
            Bs[r][c4 + 0] = v.x;
            Bs[r][c4 + 1] = v.y;
            Bs[r][c4 + 2] = v.z;
            Bs[r][c4 + 3] = v.w;
        }
        __syncthreads();
#pragma unroll
        for (int k = 0; k < BK; ++k) {
            float a[4], bb[8];
#pragma unroll
            for (int r = 0; r < 4; ++r) a[r] = As[ty * 4 + r][k];
#pragma unroll
            for (int c = 0; c < 4; ++c) bb[c] = Bs[tx * 4 + c][k];
#pragma unroll
            for (int c = 0; c < 4; ++c) bb[4 + c] = Bs[64 + tx * 4 + c][k];
#pragma unroll
            for (int r = 0; r < 4; ++r)
#pragma unroll
                for (int c = 0; c < 8; ++c) acc[r][c] += a[r] * bb[c];
        }
        __syncthreads();
    }
    const float* scb = sc + b * NLC + i0;
    const float* sqb = sq + b * NLQ;
    float* Sb = S + ((size_t)b * NLC + i0) * NLQ;
    // masks for this thread's 8 j-columns
    int qml[8];
#pragma unroll
    for (int c = 0; c < 4; ++c) { qml[c] = qm[tx * 4 + c]; qml[4 + c] = qm[64 + tx * 4 + c]; }
#pragma unroll
    for (int r = 0; r < 4; ++r) {
        int i = ty * 4 + r;
        float sci = scb[i];
        float v[8];
        v[0] = acc[r][0] + sci + sqb[tx * 4 + 0];
        v[1] = acc[r][1] + sci + sqb[tx * 4 + 1];
        v[2] = acc[r][2] + sci + sqb[tx * 4 + 2];
        v[3] = acc[r][3] + sci + sqb[tx * 4 + 3];
        v[4] = acc[r][4] + sci + sqb[64 + tx * 4 + 0];
        v[5] = acc[r][5] + sci + sqb[64 + tx * 4 + 1];
        v[6] = acc[r][6] + sci + sqb[64 + tx * 4 + 2];
        v[7] = acc[r][7] + sci + sqb[64 + tx * 4 + 3];
        float4 o0 = make_float4(v[0], v[1], v[2], v[3]);
        float4 o1 = make_float4(v[4], v[5], v[6], v[7]);
        *(float4*)&Sb[(size_t)i * NLQ + tx * 4] = o0;
        *(float4*)&Sb[(size_t)i * NLQ + 64 + tx * 4] = o1;
        // row stats over masked values
        float vm[8];
#pragma unroll
        for (int c = 0; c < 8; ++c) vm[c] = qml[c] ? NEGV : v[c];
        float m = vm[0];
#pragma unroll
        for (int c = 1; c < 8; ++c) m = fmaxf(m, vm[c]);
#pragma unroll
        for (int off = 8; off >= 1; off >>= 1) m = fmaxf(m, __shfl_xor(m, off, 64));
        float s = 0.f;
#pragma unroll
        for (int c = 0; c < 8; ++c) s += expf(vm[c] - m);
#pragma unroll
        for (int off = 8; off >= 1; off >>= 1) s += __shfl_xor(s, off, 64);
        if (tx == 0) {
            rowmax[b * NLC + i0 + i] = m;
            rowsuminv[b * NLC + i0 + i] = 1.0f / s;
        }
    }
}

// ---------------------------------------------------------------------------
// Kernel 3: column softmax partials (axis i) with Cmask. CPARTS chunks of
// NLC/CPARTS rows each; 128 threads (one per j), online max/sum.
__global__ __launch_bounds__(128) void k_colpart(const float* __restrict__ S,
                                                 const int* __restrict__ Cmask,
                                                 float* __restrict__ pm,
                                                 float* __restrict__ ps) {
    int b = blockIdx.y, part = blockIdx.x, j = threadIdx.x;
    const float* Sb = S + (size_t)b * NLC * NLQ;
    const int* cmb = Cmask + b * NLC;
    float m = -INFINITY, s = 0.f;
    int ibase = part * (NLC / CPARTS);
    for (int t = 0; t < NLC / CPARTS; ++t) {
        int i = ibase + t;
        float v = cmb[i] ? NEGV : Sb[(size_t)i * NLQ + j];
        float mn = fmaxf(m, v);
        s = s * expf(m - mn) + expf(v - mn);
        m = mn;
    }
    pm[(b * CPARTS + part) * NLQ + j] = m;
    ps[(b * CPARTS + part) * NLQ + j] = s;
}

// Kernel 4: combine the CPARTS partials per (b,j).
__global__ __launch_bounds__(128) void k_colred(const float* __restrict__ pm,
                                                const float* __restrict__ ps,
                                                float* __restrict__ colmax,
                                                float* __restrict__ colsuminv) {
    int b = blockIdx.x, j = threadIdx.x;
    float M = -INFINITY;
#pragma unroll
    for (int p = 0; p < CPARTS; ++p) M = fmaxf(M, pm[(b * CPARTS + p) * NLQ + j]);
    float s = 0.f;
#pragma unroll
    for (int p = 0; p < CPARTS; ++p) s += ps[(b * CPARTS + p) * NLQ + j] * expf(pm[(b * CPARTS + p) * NLQ + j] - M);
    colmax[b * NLQ + j] = M;
    colsuminv[b * NLQ + j] = 1.0f / s;
}

// ---------------------------------------------------------------------------
// Kernel 5: partial S2tC over a K-chunk of 128 rows of i.
// pbuf[chunk][b][j][d] partial = sum_{i in chunk} P2[b,i,j]*C[b,i,d]
// Grid (ND/64, KCH, NB), 256 threads. Tile 128(j) x 64(d), BK=16 (i).
__global__ __launch_bounds__(256) void k_S2tC_part(const float* __restrict__ S,
                                                   const float* __restrict__ C,
                                                   const int* __restrict__ Cmask,
                                                   const float* __restrict__ colmax,
                                                   const float* __restrict__ colsuminv,
                                                   float* __restrict__ pbuf) {
    constexpr int BK = 16;
    __shared__ float Ps[BK][NLQ];
    __shared__ float Cs[BK][64 + 4];
    int b = blockIdx.z, chunk = blockIdx.y, d0 = blockIdx.x * 64;
    int tid = threadIdx.x, tx = tid & 15, ty = tid >> 4;
    const float* Sb = S + (size_t)b * NLC * NLQ;
    const float* Cb = C + (size_t)b * NLC * ND;
    const int* cmb = Cmask + b * NLC;
    const float* cm = colmax + b * NLQ;
    const float* csi = colsuminv + b * NLQ;

    float acc[8][4];
#pragma unroll
    for (int r = 0; r < 8; ++r)
#pragma unroll
        for (int c = 0; c < 4; ++c) acc[r][c] = 0.f;

    int ibeg = chunk * (NLC / KCH);
    int iend = ibeg + NLC / KCH;
    for (int i0 = ibeg; i0 < iend; i0 += BK) {
#pragma unroll
        for (int t = 0; t < 8; ++t) {
            int task = tid + t * 256;
            int k = task >> 7;
            int j = task & 127;
            float v = cmb[i0 + k] ? NEGV : Sb[(size_t)(i0 + k) * NLQ + j];
            Ps[k][j] = expf(v - cm[j]) * csi[j];
        }
        {
            int k = tid >> 4;
            int c4 = (tid & 15) << 2;
            float4 v = *(const float4*)&Cb[(size_t)(i0 + k) * ND + d0 + c4];
            Cs[k][c4 + 0] = v.x;
            Cs[k][c4 + 1] = v.y;
            Cs[k][c4 + 2] = v.z;
            Cs[k][c4 + 3] = v.w;
        }
        __syncthreads();
#pragma unroll
        for (int k = 0; k < BK; ++k) {
            float a[8], bb[4];
#pragma unroll
            for (int r = 0; r < 8; ++r) a[r] = Ps[k][ty * 8 + r];
#pragma unroll
            for (int c = 0; c < 4; ++c) bb[c] = Cs[k][tx * 4 + c];
#pragma unroll
            for (int r = 0; r < 8; ++r)
#pragma unroll
                for (int c = 0; c < 4; ++c) acc[r][c] += a[r] * bb[c];
        }
        __syncthreads();
    }
    float* Ob = pbuf + ((size_t)chunk * NB + b) * NLQ * ND;
#pragma unroll
    for (int r = 0; r < 8; ++r) {
        int j = ty * 8 + r;
        float4 o;
        o.x = acc[r][0]; o.y = acc[r][1]; o.z = acc[r][2]; o.w = acc[r][3];
        *(float4*)&Ob[(size_t)j * ND + d0 + tx * 4] = o;
    }
}

// Kernel 6: reduce KCH partials -> S2tC. float4 per thread.
__global__ __launch_bounds__(256) void k_S2tC_red(const float* __restrict__ pbuf,
                                                  float* __restrict__ S2tC) {
    size_t idx4 = ((size_t)blockIdx.x * 256 + threadIdx.x) * 4;
    const size_t stride = (size_t)NB * NLQ * ND;
    float4 s = *(const float4*)&pbuf[idx4];
#pragma unroll
    for (int c = 1; c < KCH; ++c) {
        float4 v = *(const float4*)&pbuf[c * stride + idx4];
        s.x += v.x; s.y += v.y; s.z += v.z; s.w += v.w;
    }
    *(float4*)&S2tC[idx4] = s;
}

// ---------------------------------------------------------------------------
// Kernel 7: A = P1 @ Q ; Bv = P1 @ S2tC ; out = [C, A, C*A, C*Bv]
__global__ __launch_bounds__(256) void k_out(const float* __restrict__ S,
                                             const float* __restrict__ Q,
                                             const float* __restrict__ S2tC,
                                             const float* __restrict__ C,
                                             const int* __restrict__ Qmask,
                                             const float* __restrict__ rowmax,
                                             const float* __restrict__ rowsuminv,
                                             float* __restrict__ Out) {
    constexpr int BK = 32;
    __shared__ float Ps[64][BK + 1];
    __shared__ float Qs[BK][64 + 4];
    __shared__ float Vs[BK][64 + 4];
    int b = blockIdx.z, i0 = blockIdx.y * 64, d0 = blockIdx.x * 64;
    int tid = threadIdx.x, tx = tid & 15, ty = tid >> 4;
    const float* Sb = S + ((size_t)b * NLC + i0) * NLQ;
    const float* Qb = Q + (size_t)b * NLQ * ND;
    const float* Vb = S2tC + (size_t)b * NLQ * ND;
    const int* qm = Qmask + b * NLQ;
    const float* rm = rowmax + b * NLC + i0;
    const float* rsi = rowsuminv + b * NLC + i0;

    float accA[4][4], accB[4][4];
#pragma unroll
    for (int r = 0; r < 4; ++r)
#pragma unroll
        for (int c = 0; c < 4; ++c) { accA[r][c] = 0.f; accB[r][c] = 0.f; }

    for (int k0 = 0; k0 < NLQ; k0 += BK) {
#pragma unroll
        for (int t = 0; t < 2; ++t) {
            int task = tid + t * 256;
            int r = task >> 3;
            int c4 = (task & 7) << 2;
            float4 v = *(const float4*)&Sb[(size_t)r * NLQ + k0 + c4];
            float m = rm[r], si = rsi[r];
            int j = k0 + c4;
            Ps[r][c4 + 0] = qm[j + 0] ? 0.f : expf(v.x - m) * si;
            Ps[r][c4 + 1] = qm[j + 1] ? 0.f : expf(v.y - m) * si;
            Ps[r][c4 + 2] = qm[j + 2] ? 0.f : expf(v.z - m) * si;
            Ps[r][c4 + 3] = qm[j + 3] ? 0.f : expf(v.w - m) * si;
        }
#pragma unroll
        for (int t = 0; t < 2; ++t) {
            int task = tid + t * 256;
            int k = task >> 4;
            int c4 = (task & 15) << 2;
            float4 v = *(const float4*)&Qb[(size_t)(k0 + k) * ND + d0 + c4];
            Qs[k][c4 + 0] = v.x; Qs[k][c4 + 1] = v.y; Qs[k][c4 + 2] = v.z; Qs[k][c4 + 3] = v.w;
            float4 u = *(const float4*)&Vb[(size_t)(k0 + k) * ND + d0 + c4];
            Vs[k][c4 + 0] = u.x; Vs[k][c4 + 1] = u.y; Vs[k][c4 + 2] = u.z; Vs[k][c4 + 3] = u.w;
        }
        __syncthreads();
#pragma unroll
        for (int k = 0; k < BK; ++k) {
            float a[4], q4[4], v4[4];
#pragma unroll
            for (int r = 0; r < 4; ++r) a[r] = Ps[ty * 4 + r][k];
#pragma unroll
            for (int c = 0; c < 4; ++c) { q4[c] = Qs[k][tx * 4 + c]; v4[c] = Vs[k][tx * 4 + c]; }
#pragma unroll
            for (int r = 0; r < 4; ++r)
#pragma unroll
                for (int c = 0; c < 4; ++c) {
                    accA[r][c] += a[r] * q4[c];
                    accB[r][c] += a[r] * v4[c];
                }
        }
        __syncthreads();
    }

#pragma unroll
    for (int r = 0; r < 4; ++r) {
        int i = i0 + ty * 4 + r;
        float4 cv = *(const float4*)&C[((size_t)b * NLC + i) * ND + d0 + tx * 4];
        float* orow = Out + ((size_t)b * NLC + i) * (4 * ND);
        float4 av, bv, ca, cb;
        av.x = accA[r][0]; av.y = accA[r][1]; av.z = accA[r][2]; av.w = accA[r][3];
        bv.x = accB[r][0]; bv.y = accB[r][1]; bv.z = accB[r][2]; bv.w = accB[r][3];
        ca.x = cv.x * av.x; ca.y = cv.y * av.y; ca.z = cv.z * av.z; ca.w = cv.w * av.w;
        cb.x = cv.x * bv.x; cb.y = cv.y * bv.y; cb.z = cv.z * bv.z; cb.w = cv.w * bv.w;
        *(float4*)&orow[d0 + tx * 4] = cv;
        *(float4*)&orow[ND + d0 + tx * 4] = av;
        *(float4*)&orow[2 * ND + d0 + tx * 4] = ca;
        *(float4*)&orow[3 * ND + d0 + tx * 4] = cb;
    }
}

// ---------------------------------------------------------------------------
extern "C" void kernel_launch(void* const* d_in, const int* in_sizes, int n_in,
                              void* d_out, int out_size, void* d_ws, size_t ws_size,
                              hipStream_t stream) {
    const float* C = (const float*)d_in[0];
    const float* Q = (const float*)d_in[1];
    const int* Cmask = (const int*)d_in[2];
    const int* Qmask = (const int*)d_in[3];
    const float* w = (const float*)d_in[4];
    float* out = (float*)d_out;

    float* ws = (float*)d_ws;
    float* sc = ws;                               // 16384
    float* sq = sc + NB * NLC;                    // 2048
    float* S = sq + NB * NLQ;                     // 2097152
    float* rowmax = S + (size_t)NB * NLC * NLQ;   // 16384
    float* rowsuminv = rowmax + NB * NLC;         // 16384
    float* pm = rowsuminv + NB * NLC;             // 16*32*128 = 65536
    float* ps = pm + NB * CPARTS * NLQ;           // 65536
    float* colmax = ps + NB * CPARTS * NLQ;       // 2048
    float* colsuminv = colmax + NB * NLQ;         // 2048
    float* S2tC = colsuminv + NB * NLQ;           // 1048576

    // S2tC partials live in d_out (KCH * 4MB = 32MB; k_out fully overwrites
    // d_out afterwards).
    float* pbuf = out;

    k_scsq<<<dim3(NB * NLC + NB * NLQ), dim3(64), 0, stream>>>(C, Q, w, sc, sq);
    k_S<<<dim3(NLC / 64, NB), dim3(256), 0, stream>>>(C, Q, w, sc, sq, Qmask, S, rowmax, rowsuminv);
    k_colpart<<<dim3(CPARTS, NB), dim3(128), 0, stream>>>(S, Cmask, pm, ps);
    k_colred<<<dim3(NB), dim3(128), 0, stream>>>(pm, ps, colmax, colsuminv);
    k_S2tC_part<<<dim3(ND / 64, KCH, NB), dim3(256), 0, stream>>>(S, C, Cmask, colmax, colsuminv, pbuf);
    k_S2tC_red<<<dim3((NB * NLQ * ND) / (256 * 4)), dim3(256), 0, stream>>>(pbuf, S2tC);
    k_out<<<dim3(ND / 64, NLC / 64, NB), dim3(256), 0, stream>>>(S, Q, S2tC, C, Qmask, rowmax, rowsuminv, out);
}

// Round 3
// 127.757 us; speedup vs baseline: 2.9087x; 1.5115x over previous
//
#include <hip/hip_runtime.h>
#include <hip/hip_bf16.h>
#include <math.h>

#define NB 16
#define NLC 1024
#define NLQ 128
#define ND 512
#define NEGV (-1.0e10f)

typedef __attribute__((ext_vector_type(8))) short bf16x8f;
typedef __attribute__((ext_vector_type(4))) float f32x4a;

__device__ inline unsigned short f2bf(float f) {
    unsigned u = __float_as_uint(f);
    unsigned r = (u + 0x7fffu + ((u >> 16) & 1u)) >> 16;
    return (unsigned short)r;
}

// ---------------------------------------------------------------------------
// k_prep: Cw3 = bf16(C*w3), Qb = bf16(Q), sc = C@w1, sq = Q@w2.
// Blocks 0..255: C tiles (b, 64 i-rows). Blocks 256..287: Q tiles (b, 64 j-rows).
__global__ __launch_bounds__(256) void k_prep(const float* __restrict__ C,
                                              const float* __restrict__ Q,
                                              const float* __restrict__ w,
                                              unsigned short* __restrict__ Cw3,
                                              unsigned short* __restrict__ Qb,
                                              float* __restrict__ sc,
                                              float* __restrict__ sq) {
    __shared__ float part[64][2];
    int x = blockIdx.x;
    int t = threadIdx.x;
    int c4 = (t & 127) * 4;
    int rloc = t >> 7;
    int wh = (t >> 6) & 1;
    const float* src; const float* wdot; const float* wmul;
    unsigned short* dst; float* sdst;
    if (x < 256) {
        int b = x >> 4, r0 = (x & 15) * 64;
        src = C + ((size_t)b * NLC + r0) * ND;
        wdot = w;             // w1
        wmul = w + 2 * ND;    // w3
        dst = Cw3 + ((size_t)b * NLC + r0) * ND;
        sdst = sc + b * NLC + r0;
    } else {
        int x2 = x - 256;
        int b = x2 >> 1, r0 = (x2 & 1) * 64;
        src = Q + ((size_t)b * NLQ + r0) * ND;
        wdot = w + ND;        // w2
        wmul = nullptr;
        dst = Qb + ((size_t)b * NLQ + r0) * ND;
        sdst = sq + b * NLQ + r0;
    }
    float4 wd = *(const float4*)&wdot[c4];
    float4 wm = wmul ? *(const float4*)&wmul[c4] : make_float4(1.f, 1.f, 1.f, 1.f);
    for (int it = 0; it < 32; ++it) {
        int r = it * 2 + rloc;
        float4 v = *(const float4*)&src[(size_t)r * ND + c4];
        float s = v.x * wd.x + v.y * wd.y + v.z * wd.z + v.w * wd.w;
#pragma unroll
        for (int off = 32; off >= 1; off >>= 1) s += __shfl_xor(s, off, 64);
        if ((t & 63) == 0) part[r][wh] = s;
        unsigned short o[4];
        o[0] = f2bf(v.x * wm.x); o[1] = f2bf(v.y * wm.y);
        o[2] = f2bf(v.z * wm.z); o[3] = f2bf(v.w * wm.w);
        *(uint2*)&dst[(size_t)r * ND + c4] = *(uint2*)o;
    }
    __syncthreads();
    if (t < 64) sdst[t] = part[t][0] + part[t][1];
}

// ---------------------------------------------------------------------------
// k_trans: dst[b][d][r] bf16 = src[b][r][d] f32. 64x64 tiles.
__global__ __launch_bounds__(256) void k_trans(const float* __restrict__ src,
                                               unsigned short* __restrict__ dst,
                                               int rows) {
    __shared__ float T[64][65];
    int b = blockIdx.z, r0 = blockIdx.y * 64, d0 = blockIdx.x * 64;
    const float* s = src + ((size_t)b * rows + r0) * ND + d0;
    int t = threadIdx.x;
    int rr = t >> 4, cc4 = (t & 15) * 4;
#pragma unroll
    for (int p = 0; p < 4; ++p) {
        int r = rr + p * 16;
        float4 v = *(const float4*)&s[(size_t)r * ND + cc4];
        T[r][cc4 + 0] = v.x; T[r][cc4 + 1] = v.y; T[r][cc4 + 2] = v.z; T[r][cc4 + 3] = v.w;
    }
    __syncthreads();
    int dd = t >> 2, seg = (t & 3) * 16;
    unsigned short o[16];
#pragma unroll
    for (int e = 0; e < 16; ++e) o[e] = f2bf(T[seg + e][dd]);
    unsigned short* dp = dst + ((size_t)b * ND + d0 + dd) * rows + r0 + seg;
    ((int4*)dp)[0] = ((int4*)o)[0];
    ((int4*)dp)[1] = ((int4*)o)[1];
}

// ---------------------------------------------------------------------------
// k_S: MFMA bf16 GEMM  S[i][j] = Cw3[i][:] . Qb[j][:]  + sc[i] + sq[j] (K=512).
// Writes St f32 [b][j][i] (via LDS transpose) and P1 bf16 [b][i][j]
// (row-softmax over j with Qmask, stats exact in-block).
__global__ __launch_bounds__(256) void k_S(const unsigned short* __restrict__ Cw3,
                                           const unsigned short* __restrict__ Qb,
                                           const float* __restrict__ sc,
                                           const float* __restrict__ sq,
                                           const int* __restrict__ Qmask,
                                           float* __restrict__ St,
                                           unsigned short* __restrict__ P1) {
    __shared__ __align__(16) char lds[33280];  // max(As 8K + Bs 16K, Sep 33280)
    int b = blockIdx.y, i0 = blockIdx.x * 64;
    int t = threadIdx.x, lane = t & 63, wv = t >> 6;
    int g = lane >> 4, r16 = lane & 15;
    const unsigned short* Asrc = Cw3 + ((size_t)b * NLC + i0) * ND;
    const unsigned short* Bsrc = Qb + (size_t)b * NLQ * ND;
    f32x4a zero = {0.f, 0.f, 0.f, 0.f};
    f32x4a acc[8];
#pragma unroll
    for (int nf = 0; nf < 8; ++nf) acc[nf] = zero;

    for (int kk = 0; kk < 8; ++kk) {
#pragma unroll
        for (int p = 0; p < 2; ++p) {  // A: 64 rows x 64 d = 512 16B units
            int u = t + p * 256;
            int i = u >> 3, db = u & 7;
            int4 v = *(const int4*)(Asrc + (size_t)i * ND + kk * 64 + db * 8);
            *(int4*)(lds + i * 128 + ((db * 16) ^ ((i & 7) << 4))) = v;
        }
#pragma unroll
        for (int p = 0; p < 4; ++p) {  // B: 128 rows x 64 d
            int u = t + p * 256;
            int j = u >> 3, db = u & 7;
            int4 v = *(const int4*)(Bsrc + (size_t)j * ND + kk * 64 + db * 8);
            *(int4*)(lds + 8192 + j * 128 + ((db * 16) ^ ((j & 7) << 4))) = v;
        }
        __syncthreads();
#pragma unroll
        for (int ks = 0; ks < 2; ++ks) {
            int inner = ks * 64 + g * 16;
            bf16x8f a = *(const bf16x8f*)(lds + (16 * wv + r16) * 128 + (inner ^ ((r16 & 7) << 4)));
#pragma unroll
            for (int nf = 0; nf < 8; ++nf) {
                bf16x8f bq = *(const bf16x8f*)(lds + 8192 + (16 * nf + r16) * 128 + (inner ^ ((r16 & 7) << 4)));
                acc[nf] = __builtin_amdgcn_mfma_f32_16x16x32_bf16(a, bq, acc[nf], 0, 0, 0);
            }
        }
        __syncthreads();
    }

    // Epilogue. i = i0 + 16wv + 4g + reg ; j = 16nf + r16.
    const float* scp = sc + b * NLC + i0;
    const float* sqp = sq + b * NLQ;
    const int* qm = Qmask + b * NLQ;
    float sv[8][4];
    float scr[4];
#pragma unroll
    for (int reg = 0; reg < 4; ++reg) scr[reg] = scp[16 * wv + 4 * g + reg];
    int qmv[8];
#pragma unroll
    for (int nf = 0; nf < 8; ++nf) {
        qmv[nf] = qm[16 * nf + r16];
        float sqv = sqp[16 * nf + r16];
#pragma unroll
        for (int reg = 0; reg < 4; ++reg) sv[nf][reg] = acc[nf][reg] + scr[reg] + sqv;
    }
    unsigned short* P1p = P1 + ((size_t)b * NLC + i0) * NLQ;
#pragma unroll
    for (int reg = 0; reg < 4; ++reg) {
        float m = -INFINITY;
#pragma unroll
        for (int nf = 0; nf < 8; ++nf) {
            float vm = qmv[nf] ? NEGV : sv[nf][reg];
            m = fmaxf(m, vm);
        }
#pragma unroll
        for (int off = 8; off >= 1; off >>= 1) m = fmaxf(m, __shfl_xor(m, off, 64));
        float pv[8], s = 0.f;
#pragma unroll
        for (int nf = 0; nf < 8; ++nf) {
            float vm = qmv[nf] ? NEGV : sv[nf][reg];
            pv[nf] = __expf(vm - m);
            s += pv[nf];
        }
#pragma unroll
        for (int off = 8; off >= 1; off >>= 1) s += __shfl_xor(s, off, 64);
        float rsi = 1.0f / s;
        int i = 16 * wv + 4 * g + reg;
#pragma unroll
        for (int nf = 0; nf < 8; ++nf)
            P1p[(size_t)i * NLQ + 16 * nf + r16] = f2bf(pv[nf] * rsi);
    }

    // St f32 [j][i] via LDS transpose (lds free after final sync above).
    float* Sep = (float*)lds;
#pragma unroll
    for (int nf = 0; nf < 8; ++nf)
#pragma unroll
        for (int reg = 0; reg < 4; ++reg)
            Sep[(16 * nf + r16) * 65 + 16 * wv + 4 * g + reg] = sv[nf][reg];
    __syncthreads();
    {
        int j = t >> 1, half = t & 1;
        float* Stp = St + ((size_t)b * NLQ + j) * NLC + i0 + half * 32;
#pragma unroll
        for (int c = 0; c < 8; ++c) {
            float4 v;
            v.x = Sep[j * 65 + half * 32 + c * 4 + 0];
            v.y = Sep[j * 65 + half * 32 + c * 4 + 1];
            v.z = Sep[j * 65 + half * 32 + c * 4 + 2];
            v.w = Sep[j * 65 + half * 32 + c * 4 + 3];
            *(float4*)&Stp[c * 4] = v;
        }
    }
}

// ---------------------------------------------------------------------------
// k_colstat: column softmax stats (over i) per (b,j). One wave per St row.
__global__ __launch_bounds__(256) void k_colstat(const float* __restrict__ St,
                                                 const int* __restrict__ Cmask,
                                                 float* __restrict__ colmax,
                                                 float* __restrict__ colsuminv) {
    int row = blockIdx.x * 4 + (threadIdx.x >> 6);
    int lane = threadIdx.x & 63;
    int b = row >> 7;
    const float* sp = St + (size_t)row * NLC;
    const int* cm = Cmask + b * NLC;
    float vv[16];
    float m = -INFINITY;
#pragma unroll
    for (int tt = 0; tt < 16; ++tt) {
        int i = lane + tt * 64;
        float v = cm[i] ? NEGV : sp[i];
        vv[tt] = v;
        m = fmaxf(m, v);
    }
#pragma unroll
    for (int off = 32; off >= 1; off >>= 1) m = fmaxf(m, __shfl_xor(m, off, 64));
    float s = 0.f;
#pragma unroll
    for (int tt = 0; tt < 16; ++tt) s += __expf(vv[tt] - m);
#pragma unroll
    for (int off = 32; off >= 1; off >>= 1) s += __shfl_xor(s, off, 64);
    if (lane == 0) { colmax[row] = m; colsuminv[row] = 1.0f / s; }
}

// ---------------------------------------------------------------------------
// k_s2tc: partial S2tC[j][d] = sum_{i in chunk} P2[i][j] * C[i][d], MFMA,
// P2 from St + col stats on the fly. pbuf[kc][b][d][j] f32.
__global__ __launch_bounds__(256) void k_s2tc(const float* __restrict__ St,
                                              const unsigned short* __restrict__ Ct,
                                              const int* __restrict__ Cmask,
                                              const float* __restrict__ colmax,
                                              const float* __restrict__ colsuminv,
                                              float* __restrict__ pbuf) {
    __shared__ __align__(16) char lds[15360];  // Ps [128][40]bf16 @0, Cs [64][40]bf16 @10240
    int dt = blockIdx.x, kc = blockIdx.y, b = blockIdx.z;
    int t = threadIdx.x, lane = t & 63, wv = t >> 6, g = lane >> 4, r16 = lane & 15;
    const float* Stb = St + (size_t)b * NLQ * NLC;
    const unsigned short* Ctb = Ct + ((size_t)b * ND + dt * 64) * NLC;
    const int* cmk = Cmask + b * NLC;
    const float* cmx = colmax + b * NLQ;
    const float* csi = colsuminv + b * NLQ;
    f32x4a zero = {0.f, 0.f, 0.f, 0.f};
    f32x4a acc[2][4];
#pragma unroll
    for (int mf = 0; mf < 2; ++mf)
#pragma unroll
        for (int nf = 0; nf < 4; ++nf) acc[mf][nf] = zero;

    for (int is = 0; is < 8; ++is) {
        int ib = kc * 256 + is * 32;
#pragma unroll
        for (int p = 0; p < 4; ++p) {  // Ps: 128 j-rows x 32 i f32 -> exp -> bf16
            int u = t + p * 256;
            int j = u >> 3, c4 = (u & 7) * 4;
            float4 v = *(const float4*)(Stb + (size_t)j * NLC + ib + c4);
            float M = cmx[j], SI = csi[j];
            float vf[4] = {v.x, v.y, v.z, v.w};
            unsigned short o[4];
#pragma unroll
            for (int e = 0; e < 4; ++e) {
                float vm = cmk[ib + c4 + e] ? NEGV : vf[e];
                o[e] = f2bf(__expf(vm - M) * SI);
            }
            *(uint2*)(lds + (j * 40 + c4) * 2) = *(uint2*)o;
        }
        {  // Cs: 64 d-rows x 32 bf16
            int dd = t >> 2, c8 = (t & 3) * 8;
            int4 v = *(const int4*)(Ctb + (size_t)dd * NLC + ib + c8);
            *(int4*)(lds + 10240 + (dd * 40 + c8) * 2) = v;
        }
        __syncthreads();
#pragma unroll
        for (int mf = 0; mf < 2; ++mf) {
            bf16x8f a = *(const bf16x8f*)(lds + ((32 * wv + 16 * mf + r16) * 40 + g * 8) * 2);
#pragma unroll
            for (int nf = 0; nf < 4; ++nf) {
                bf16x8f bb = *(const bf16x8f*)(lds + 10240 + ((16 * nf + r16) * 40 + g * 8) * 2);
                acc[mf][nf] = __builtin_amdgcn_mfma_f32_16x16x32_bf16(a, bb, acc[mf][nf], 0, 0, 0);
            }
        }
        __syncthreads();
    }
    // pbuf[kc][b][d][j]: d = dt*64+16nf+r16, j = 32wv+16mf+4g+reg (float4 over reg)
    float* pb = pbuf + (((size_t)kc * NB + b) * ND + dt * 64) * NLQ;
#pragma unroll
    for (int mf = 0; mf < 2; ++mf)
#pragma unroll
        for (int nf = 0; nf < 4; ++nf) {
            float4 v;
            v.x = acc[mf][nf][0]; v.y = acc[mf][nf][1];
            v.z = acc[mf][nf][2]; v.w = acc[mf][nf][3];
            *(float4*)&pb[(size_t)(16 * nf + r16) * NLQ + 32 * wv + 16 * mf + 4 * g] = v;
        }
}

// ---------------------------------------------------------------------------
// k_red: Vt bf16 [b][d][j] = sum of 4 pbuf chunks.
__global__ __launch_bounds__(256) void k_red(const float* __restrict__ pbuf,
                                             unsigned short* __restrict__ Vt) {
    size_t u = (size_t)blockIdx.x * 256 + threadIdx.x;
    const size_t cs = (size_t)NB * ND * NLQ;
    float4 s = *(const float4*)&pbuf[u * 4];
#pragma unroll
    for (int c = 1; c < 4; ++c) {
        float4 v = *(const float4*)&pbuf[cs * c + u * 4];
        s.x += v.x; s.y += v.y; s.z += v.z; s.w += v.w;
    }
    unsigned short o[4] = {f2bf(s.x), f2bf(s.y), f2bf(s.z), f2bf(s.w)};
    *(uint2*)&Vt[u * 4] = *(uint2*)o;
}

// ---------------------------------------------------------------------------
// k_out: A = P1@Qt^T, Bv = P1@Vt^T (K=128, MFMA); out = [C, A, C*A, C*Bv].
__global__ __launch_bounds__(256) void k_out(const unsigned short* __restrict__ P1,
                                             const unsigned short* __restrict__ Qt,
                                             const unsigned short* __restrict__ Vt,
                                             const float* __restrict__ C,
                                             float* __restrict__ Out) {
    __shared__ __align__(16) char lds[49152];  // P1s@0, Qts@16384, Vts@32768: [64][256B]
    int dt = blockIdx.x, it = blockIdx.y, b = blockIdx.z;
    int i0 = it * 64, d0 = dt * 64;
    int t = threadIdx.x, lane = t & 63, wv = t >> 6, g = lane >> 4, r16 = lane & 15;
    const unsigned short* P1b = P1 + ((size_t)b * NLC + i0) * NLQ;
    const unsigned short* Qtb = Qt + ((size_t)b * ND + d0) * NLQ;
    const unsigned short* Vtb = Vt + ((size_t)b * ND + d0) * NLQ;
#pragma unroll
    for (int p = 0; p < 4; ++p) {
        int u = t + p * 256;
        int r = u >> 4, c = u & 15;
        int swz = (c * 16) ^ ((r & 7) << 4);
        *(int4*)(lds + r * 256 + swz) = *(const int4*)(P1b + (size_t)r * NLQ + c * 8);
        *(int4*)(lds + 16384 + r * 256 + swz) = *(const int4*)(Qtb + (size_t)r * NLQ + c * 8);
        *(int4*)(lds + 32768 + r * 256 + swz) = *(const int4*)(Vtb + (size_t)r * NLQ + c * 8);
    }
    __syncthreads();
    f32x4a zero = {0.f, 0.f, 0.f, 0.f};
    f32x4a accA[4], accB[4];
#pragma unroll
    for (int nf = 0; nf < 4; ++nf) { accA[nf] = zero; accB[nf] = zero; }
#pragma unroll
    for (int ks = 0; ks < 4; ++ks) {
        int inner = ks * 64 + g * 16;
        bf16x8f a = *(const bf16x8f*)(lds + (16 * wv + r16) * 256 + (inner ^ ((r16 & 7) << 4)));
#pragma unroll
        for (int nf = 0; nf < 4; ++nf) {
            int ro = (16 * nf + r16) * 256 + (inner ^ ((r16 & 7) << 4));
            bf16x8f q = *(const bf16x8f*)(lds + 16384 + ro);
            accA[nf] = __builtin_amdgcn_mfma_f32_16x16x32_bf16(a, q, accA[nf], 0, 0, 0);
            bf16x8f vv = *(const bf16x8f*)(lds + 32768 + ro);
            accB[nf] = __builtin_amdgcn_mfma_f32_16x16x32_bf16(a, vv, accB[nf], 0, 0, 0);
        }
    }
#pragma unroll
    for (int nf = 0; nf < 4; ++nf) {
        int d = d0 + 16 * nf + r16;
#pragma unroll
        for (int reg = 0; reg < 4; ++reg) {
            int i = i0 + 16 * wv + 4 * g + reg;
            float cv = C[((size_t)b * NLC + i) * ND + d];
            float av = accA[nf][reg], bv = accB[nf][reg];
            float* orow = Out + ((size_t)b * NLC + i) * (4 * ND);
            orow[d] = cv;
            orow[ND + d] = av;
            orow[2 * ND + d] = cv * av;
            orow[3 * ND + d] = cv * bv;
        }
    }
}

// ---------------------------------------------------------------------------
extern "C" void kernel_launch(void* const* d_in, const int* in_sizes, int n_in,
                              void* d_out, int out_size, void* d_ws, size_t ws_size,
                              hipStream_t stream) {
    const float* C = (const float*)d_in[0];
    const float* Q = (const float*)d_in[1];
    const int* Cmask = (const int*)d_in[2];
    const int* Qmask = (const int*)d_in[3];
    const float* w = (const float*)d_in[4];
    float* out = (float*)d_out;

    // Large early-stage scratch lives in d_out (all consumed before k_out,
    // which fully overwrites d_out). 60.8 MB used of 134 MB.
    char* ob = (char*)d_out;
    unsigned short* Cw3 = (unsigned short*)(ob + 0);          // 16,777,216 B
    unsigned short* Ct  = (unsigned short*)(ob + 16777216);   // 16,777,216 B
    float*          St  = (float*)(ob + 33554432);            //  8,388,608 B
    unsigned short* Qb  = (unsigned short*)(ob + 41943040);   //  2,097,152 B
    float*          pbuf = (float*)(ob + 44040192);           // 16,777,216 B

    // Final-stage scratch in ws (read while k_out writes d_out): 8.5 MB.
    char* wb = (char*)d_ws;
    float* sc        = (float*)(wb + 0);        // 65,536 B
    float* sq        = (float*)(wb + 65536);    //  8,192 B
    float* colmax    = (float*)(wb + 73728);    //  8,192 B
    float* colsuminv = (float*)(wb + 81920);    //  8,192 B
    unsigned short* P1 = (unsigned short*)(wb + 90112);    // 4,194,304 B
    unsigned short* Qt = (unsigned short*)(wb + 4284416);  // 2,097,152 B
    unsigned short* Vt = (unsigned short*)(wb + 6381568);  // 2,097,152 B

    k_prep<<<dim3(288), dim3(256), 0, stream>>>(C, Q, w, Cw3, Qb, sc, sq);
    k_trans<<<dim3(8, 16, 16), dim3(256), 0, stream>>>(C, Ct, NLC);
    k_trans<<<dim3(8, 2, 16), dim3(256), 0, stream>>>(Q, Qt, NLQ);
    k_S<<<dim3(16, 16), dim3(256), 0, stream>>>(Cw3, Qb, sc, sq, Qmask, St, P1);
    k_colstat<<<dim3(512), dim3(256), 0, stream>>>(St, Cmask, colmax, colsuminv);
    k_s2tc<<<dim3(8, 4, 16), dim3(256), 0, stream>>>(St, Ct, Cmask, colmax, colsuminv, pbuf);
    k_red<<<dim3(1024), dim3(256), 0, stream>>>(pbuf, Vt);
    k_out<<<dim3(8, 16, 16), dim3(256), 0, stream>>>(P1, Qt, Vt, C, out);
}

// Round 4
// 95.294 us; speedup vs baseline: 3.8996x; 1.3407x over previous
//
#include <hip/hip_runtime.h>
#include <hip/hip_bf16.h>
#include <math.h>

#define NB 16
#define NLC 1024
#define NLQ 128
#define ND 512
#define NEGV (-1.0e10f)

typedef __attribute__((ext_vector_type(8))) short bf16x8f;
typedef __attribute__((ext_vector_type(4))) float f32x4a;

__device__ inline unsigned short f2bf(float f) {
    unsigned u = __float_as_uint(f);
    unsigned r = (u + 0x7fffu + ((u >> 16) & 1u)) >> 16;
    return (unsigned short)r;
}

// ---------------------------------------------------------------------------
// k_prep2: single pass over C and Q producing
//   Cw3 bf16 [b][i][d] = C*w3 ; Ct bf16 [b][d][i] = C^T ; sc = C@w1
//   Qb  bf16 [b][j][d] = Q    ; Qt bf16 [b][d][j] = Q^T ; sq = Q@w2
// Blocks 0..255: C (b, 64-row tile). Blocks 256..287: Q.
__global__ __launch_bounds__(256) void k_prep2(const float* __restrict__ C,
                                               const float* __restrict__ Q,
                                               const float* __restrict__ w,
                                               unsigned short* __restrict__ Cw3,
                                               unsigned short* __restrict__ Ct,
                                               unsigned short* __restrict__ Qb,
                                               unsigned short* __restrict__ Qt,
                                               float* __restrict__ sc,
                                               float* __restrict__ sq) {
    __shared__ float T[64][65];
    int x = blockIdx.x, t = threadIdx.x;
    const float* src; const float* wdot; const float* wmul;
    unsigned short* rout; unsigned short* tout; float* sdst;
    int rows;
    if (x < 256) {
        int b = x >> 4, r0 = (x & 15) * 64;
        src = C + ((size_t)b * NLC + r0) * ND;
        wdot = w; wmul = w + 2 * ND;
        rout = Cw3 + ((size_t)b * NLC + r0) * ND;
        tout = Ct + (size_t)b * ND * NLC + r0;
        sdst = sc + b * NLC + r0;
        rows = NLC;
    } else {
        int x2 = x - 256;
        int b = x2 >> 1, r0 = (x2 & 1) * 64;
        src = Q + ((size_t)b * NLQ + r0) * ND;
        wdot = w + ND; wmul = nullptr;
        rout = Qb + ((size_t)b * NLQ + r0) * ND;
        tout = Qt + (size_t)b * ND * NLQ + r0;
        sdst = sq + b * NLQ + r0;
        rows = NLQ;
    }
    int r = t >> 2, s4 = (t & 3) * 16;
    float dacc = 0.f;
    for (int c = 0; c < 8; ++c) {
        int dbase = c * 64 + s4;
#pragma unroll
        for (int k = 0; k < 4; ++k) {
            float4 v = *(const float4*)&src[(size_t)r * ND + dbase + k * 4];
            float4 wd = *(const float4*)&wdot[dbase + k * 4];
            dacc += v.x * wd.x + v.y * wd.y + v.z * wd.z + v.w * wd.w;
            float4 vm;
            if (wmul) {
                float4 w3v = *(const float4*)&wmul[dbase + k * 4];
                vm = make_float4(v.x * w3v.x, v.y * w3v.y, v.z * w3v.z, v.w * w3v.w);
            } else {
                vm = v;
            }
            unsigned short o[4] = {f2bf(vm.x), f2bf(vm.y), f2bf(vm.z), f2bf(vm.w)};
            *(uint2*)&rout[(size_t)r * ND + dbase + k * 4] = *(uint2*)o;
            T[r][s4 + k * 4 + 0] = v.x;
            T[r][s4 + k * 4 + 1] = v.y;
            T[r][s4 + k * 4 + 2] = v.z;
            T[r][s4 + k * 4 + 3] = v.w;
        }
        __syncthreads();
        {   // transposed output: bf16(C) / bf16(Q)
            int dd = t >> 2, seg = (t & 3) * 16;
            unsigned short o16[16];
#pragma unroll
            for (int e = 0; e < 16; ++e) o16[e] = f2bf(T[seg + e][dd]);
            unsigned short* dp = tout + (size_t)(c * 64 + dd) * rows + seg;
            ((int4*)dp)[0] = ((int4*)o16)[0];
            ((int4*)dp)[1] = ((int4*)o16)[1];
        }
        __syncthreads();
    }
    dacc += __shfl_xor(dacc, 1, 64);
    dacc += __shfl_xor(dacc, 2, 64);
    if ((t & 3) == 0) sdst[r] = dacc;
}

// ---------------------------------------------------------------------------
// k_S: MFMA bf16 GEMM  S[i][j] = Cw3[i][:].Qb[j][:] + sc[i] + sq[j]  (K=512).
// Epilogue: row softmax (Qmask) -> P1 bf16 [b][i][j];
//           column partials (m,s per j over this 64-i tile, Cmask) -> colm/cols;
//           E bf16 [b][j][i] = exp(masked S - m_tile[j]) (LDS-transposed).
__global__ __launch_bounds__(256) void k_S(const unsigned short* __restrict__ Cw3,
                                           const unsigned short* __restrict__ Qb,
                                           const float* __restrict__ sc,
                                           const float* __restrict__ sq,
                                           const int* __restrict__ Qmask,
                                           const int* __restrict__ Cmask,
                                           unsigned short* __restrict__ P1,
                                           unsigned short* __restrict__ Eb,
                                           float* __restrict__ colm,
                                           float* __restrict__ cols) {
    __shared__ __align__(16) char lds[25088];
    int b = blockIdx.y, it = blockIdx.x, i0 = it * 64;
    int t = threadIdx.x, lane = t & 63, wv = t >> 6;
    int g = lane >> 4, r16 = lane & 15;
    const unsigned short* Asrc = Cw3 + ((size_t)b * NLC + i0) * ND;
    const unsigned short* Bsrc = Qb + (size_t)b * NLQ * ND;
    f32x4a zero = {0.f, 0.f, 0.f, 0.f};
    f32x4a acc[8];
#pragma unroll
    for (int nf = 0; nf < 8; ++nf) acc[nf] = zero;

    for (int kk = 0; kk < 8; ++kk) {
#pragma unroll
        for (int p = 0; p < 2; ++p) {  // A: 64 rows x 64 d
            int u = t + p * 256;
            int i = u >> 3, db = u & 7;
            int4 v = *(const int4*)(Asrc + (size_t)i * ND + kk * 64 + db * 8);
            *(int4*)(lds + i * 128 + ((db * 16) ^ ((i & 7) << 4))) = v;
        }
#pragma unroll
        for (int p = 0; p < 4; ++p) {  // B: 128 rows x 64 d
            int u = t + p * 256;
            int j = u >> 3, db = u & 7;
            int4 v = *(const int4*)(Bsrc + (size_t)j * ND + kk * 64 + db * 8);
            *(int4*)(lds + 8192 + j * 128 + ((db * 16) ^ ((j & 7) << 4))) = v;
        }
        __syncthreads();
#pragma unroll
        for (int ks = 0; ks < 2; ++ks) {
            int inner = ks * 64 + g * 16;
            bf16x8f a = *(const bf16x8f*)(lds + (16 * wv + r16) * 128 + (inner ^ ((r16 & 7) << 4)));
#pragma unroll
            for (int nf = 0; nf < 8; ++nf) {
                bf16x8f bq = *(const bf16x8f*)(lds + 8192 + (16 * nf + r16) * 128 + (inner ^ ((r16 & 7) << 4)));
                acc[nf] = __builtin_amdgcn_mfma_f32_16x16x32_bf16(a, bq, acc[nf], 0, 0, 0);
            }
        }
        __syncthreads();
    }

    // sv[nf][reg]: i = i0 + 16wv + 4g + reg ; j = 16nf + r16
    const float* scp = sc + b * NLC + i0;
    const float* sqp = sq + b * NLQ;
    const int* qm = Qmask + b * NLQ;
    const int* cmb = Cmask + b * NLC;
    float sv[8][4];
    float scr[4];
#pragma unroll
    for (int reg = 0; reg < 4; ++reg) scr[reg] = scp[16 * wv + 4 * g + reg];
    int qmv[8];
#pragma unroll
    for (int nf = 0; nf < 8; ++nf) {
        qmv[nf] = qm[16 * nf + r16];
        float sqv = sqp[16 * nf + r16];
#pragma unroll
        for (int reg = 0; reg < 4; ++reg) sv[nf][reg] = acc[nf][reg] + scr[reg] + sqv;
    }

    // ---- row softmax -> P1 ----
    unsigned short* P1p = P1 + ((size_t)b * NLC + i0) * NLQ;
#pragma unroll
    for (int reg = 0; reg < 4; ++reg) {
        float m = -INFINITY;
#pragma unroll
        for (int nf = 0; nf < 8; ++nf) m = fmaxf(m, qmv[nf] ? NEGV : sv[nf][reg]);
#pragma unroll
        for (int off = 8; off >= 1; off >>= 1) m = fmaxf(m, __shfl_xor(m, off, 64));
        float pv[8], s = 0.f;
#pragma unroll
        for (int nf = 0; nf < 8; ++nf) {
            pv[nf] = __expf((qmv[nf] ? NEGV : sv[nf][reg]) - m);
            s += pv[nf];
        }
#pragma unroll
        for (int off = 8; off >= 1; off >>= 1) s += __shfl_xor(s, off, 64);
        float rsi = 1.0f / s;
        int i = 16 * wv + 4 * g + reg;
#pragma unroll
        for (int nf = 0; nf < 8; ++nf)
            P1p[(size_t)i * NLQ + 16 * nf + r16] = f2bf(pv[nf] * rsi);
    }

    // ---- column partials over this tile's 64 i's ----
    int cmv[4];
#pragma unroll
    for (int reg = 0; reg < 4; ++reg) cmv[reg] = cmb[i0 + 16 * wv + 4 * g + reg];
    float vm2[8][4];
#pragma unroll
    for (int nf = 0; nf < 8; ++nf)
#pragma unroll
        for (int reg = 0; reg < 4; ++reg) vm2[nf][reg] = cmv[reg] ? NEGV : sv[nf][reg];

    float* cpm = (float*)(lds + 20480);
    float* cps = (float*)(lds + 22528);
    float* mtl = (float*)(lds + 24576);
    float cm8[8], cs8[8];
#pragma unroll
    for (int nf = 0; nf < 8; ++nf) {
        float m = vm2[nf][0];
#pragma unroll
        for (int reg = 1; reg < 4; ++reg) m = fmaxf(m, vm2[nf][reg]);
        float s = 0.f;
#pragma unroll
        for (int reg = 0; reg < 4; ++reg) s += __expf(vm2[nf][reg] - m);
#pragma unroll
        for (int off = 16; off <= 32; off <<= 1) {
            float mo = __shfl_xor(m, off, 64);
            float so = __shfl_xor(s, off, 64);
            float mn = fmaxf(m, mo);
            s = s * __expf(m - mn) + so * __expf(mo - mn);
            m = mn;
        }
        cm8[nf] = m; cs8[nf] = s;
    }
    if (g == 0) {
#pragma unroll
        for (int nf = 0; nf < 8; ++nf) {
            cpm[(wv * 8 + nf) * 16 + r16] = cm8[nf];
            cps[(wv * 8 + nf) * 16 + r16] = cs8[nf];
        }
    }
    __syncthreads();
    if (t < 128) {
        int j = t, nf = j >> 4, rr = j & 15;
        float M = cpm[(0 * 8 + nf) * 16 + rr];
        float S = cps[(0 * 8 + nf) * 16 + rr];
#pragma unroll
        for (int w2 = 1; w2 < 4; ++w2) {
            float mo = cpm[(w2 * 8 + nf) * 16 + rr];
            float so = cps[(w2 * 8 + nf) * 16 + rr];
            float mn = fmaxf(M, mo);
            S = S * __expf(M - mn) + so * __expf(mo - mn);
            M = mn;
        }
        colm[((size_t)b * 16 + it) * NLQ + j] = M;
        cols[((size_t)b * 16 + it) * NLQ + j] = S;
        mtl[j] = M;
    }
    __syncthreads();

    // ---- E bf16 [b][j][i] via LDS transpose ----
    unsigned short* ex = (unsigned short*)lds;  // [128][80]
#pragma unroll
    for (int nf = 0; nf < 8; ++nf) {
        float mj = mtl[16 * nf + r16];
        unsigned short e4[4];
#pragma unroll
        for (int reg = 0; reg < 4; ++reg) e4[reg] = f2bf(__expf(vm2[nf][reg] - mj));
        *(uint2*)&ex[(16 * nf + r16) * 80 + 16 * wv + 4 * g] = *(uint2*)e4;
    }
    __syncthreads();
    {
        int j = t >> 1, half = t & 1;
        unsigned short* Ep = Eb + ((size_t)b * NLQ + j) * NLC + i0 + half * 32;
#pragma unroll
        for (int c = 0; c < 4; ++c)
            *(int4*)&Ep[c * 8] = *(int4*)&ex[j * 80 + half * 32 + c * 8];
    }
}

// ---------------------------------------------------------------------------
// k_s2tc: pbuf[kc][b][d][j] = sum_{it in kc} f[it][j] * (E_it^T Ct_it)[j][d]
// f[it][j] = exp(colm[it][j]-M[j]) / S[j] computed in-block from colm/cols.
__global__ __launch_bounds__(256) void k_s2tc(const unsigned short* __restrict__ Eb,
                                              const unsigned short* __restrict__ Ct,
                                              const float* __restrict__ colm,
                                              const float* __restrict__ cols,
                                              float* __restrict__ pbuf) {
    __shared__ __align__(16) char lds[23552];  // f @0 (8K), A @8192 (10240), B @18432 (5120)
    int dt = blockIdx.x, kc = blockIdx.y, b = blockIdx.z;
    int t = threadIdx.x, lane = t & 63, wv = t >> 6, g = lane >> 4, r16 = lane & 15;
    float* fb = (float*)lds;

    if (t < 128) {  // global col stats + per-tile scale f
        int j = t;
        const float* cmp = colm + (size_t)b * 16 * NLQ + j;
        const float* csp = cols + (size_t)b * 16 * NLQ + j;
        float M = -INFINITY;
#pragma unroll
        for (int p = 0; p < 16; ++p) M = fmaxf(M, cmp[p * NLQ]);
        float S = 0.f;
#pragma unroll
        for (int p = 0; p < 16; ++p) S += csp[p * NLQ] * __expf(cmp[p * NLQ] - M);
        float inv = 1.0f / S;
#pragma unroll
        for (int p = 0; p < 16; ++p) fb[p * NLQ + j] = __expf(cmp[p * NLQ] - M) * inv;
    }
    __syncthreads();

    const unsigned short* Ebb = Eb + (size_t)b * NLQ * NLC;
    const unsigned short* Ctb = Ct + ((size_t)b * ND + dt * 64) * NLC;
    f32x4a zero = {0.f, 0.f, 0.f, 0.f};
    f32x4a acc2[2][4], V[2][4];
#pragma unroll
    for (int mf = 0; mf < 2; ++mf)
#pragma unroll
        for (int nf = 0; nf < 4; ++nf) { acc2[mf][nf] = zero; V[mf][nf] = zero; }

    for (int ib = kc * 256; ib < kc * 256 + 256; ib += 32) {
#pragma unroll
        for (int p = 0; p < 2; ++p) {  // A: E slice 128 j x 32 i
            int u = t + p * 256;
            int j = u >> 2, c8 = (u & 3) * 8;
            int4 v = *(const int4*)(Ebb + (size_t)j * NLC + ib + c8);
            *(int4*)(lds + 8192 + (j * 40 + c8) * 2) = v;
        }
        {   // B: Ct slice 64 d x 32 i
            int dd = t >> 2, c8 = (t & 3) * 8;
            int4 v = *(const int4*)(Ctb + (size_t)dd * NLC + ib + c8);
            *(int4*)(lds + 18432 + (dd * 40 + c8) * 2) = v;
        }
        __syncthreads();
#pragma unroll
        for (int mf = 0; mf < 2; ++mf) {
            bf16x8f a = *(const bf16x8f*)(lds + 8192 + ((32 * wv + 16 * mf + r16) * 40 + g * 8) * 2);
#pragma unroll
            for (int nf = 0; nf < 4; ++nf) {
                bf16x8f bb = *(const bf16x8f*)(lds + 18432 + ((16 * nf + r16) * 40 + g * 8) * 2);
                acc2[mf][nf] = __builtin_amdgcn_mfma_f32_16x16x32_bf16(a, bb, acc2[mf][nf], 0, 0, 0);
            }
        }
        __syncthreads();
        if (ib & 32) {  // finished an i-tile of 64: apply f and fold into V
            int itg = ib >> 6;
#pragma unroll
            for (int mf = 0; mf < 2; ++mf) {
                f32x4a f4 = *(const f32x4a*)(lds + (itg * NLQ + 32 * wv + 16 * mf + 4 * g) * 4);
#pragma unroll
                for (int nf = 0; nf < 4; ++nf) {
#pragma unroll
                    for (int reg = 0; reg < 4; ++reg)
                        V[mf][nf][reg] += f4[reg] * acc2[mf][nf][reg];
                    acc2[mf][nf] = zero;
                }
            }
        }
    }
    float* pb = pbuf + (((size_t)kc * NB + b) * ND + dt * 64) * NLQ;
#pragma unroll
    for (int mf = 0; mf < 2; ++mf)
#pragma unroll
        for (int nf = 0; nf < 4; ++nf) {
            float4 v;
            v.x = V[mf][nf][0]; v.y = V[mf][nf][1];
            v.z = V[mf][nf][2]; v.w = V[mf][nf][3];
            *(float4*)&pb[(size_t)(16 * nf + r16) * NLQ + 32 * wv + 16 * mf + 4 * g] = v;
        }
}

// ---------------------------------------------------------------------------
// k_red: Vt bf16 [b][d][j] = sum of 4 pbuf chunks.
__global__ __launch_bounds__(256) void k_red(const float* __restrict__ pbuf,
                                             unsigned short* __restrict__ Vt) {
    size_t u = (size_t)blockIdx.x * 256 + threadIdx.x;
    const size_t cs = (size_t)NB * ND * NLQ;
    float4 s = *(const float4*)&pbuf[u * 4];
#pragma unroll
    for (int c = 1; c < 4; ++c) {
        float4 v = *(const float4*)&pbuf[cs * c + u * 4];
        s.x += v.x; s.y += v.y; s.z += v.z; s.w += v.w;
    }
    unsigned short o[4] = {f2bf(s.x), f2bf(s.y), f2bf(s.z), f2bf(s.w)};
    *(uint2*)&Vt[u * 4] = *(uint2*)o;
}

// ---------------------------------------------------------------------------
// k_out: A = P1@Qt^T, Bv = P1@Vt^T (K=128, MFMA); out = [C, A, C*A, C*Bv].
__global__ __launch_bounds__(256) void k_out(const unsigned short* __restrict__ P1,
                                             const unsigned short* __restrict__ Qt,
                                             const unsigned short* __restrict__ Vt,
                                             const float* __restrict__ C,
                                             float* __restrict__ Out) {
    __shared__ __align__(16) char lds[49152];
    int dt = blockIdx.x, it = blockIdx.y, b = blockIdx.z;
    int i0 = it * 64, d0 = dt * 64;
    int t = threadIdx.x, lane = t & 63, wv = t >> 6, g = lane >> 4, r16 = lane & 15;
    const unsigned short* P1b = P1 + ((size_t)b * NLC + i0) * NLQ;
    const unsigned short* Qtb = Qt + ((size_t)b * ND + d0) * NLQ;
    const unsigned short* Vtb = Vt + ((size_t)b * ND + d0) * NLQ;
#pragma unroll
    for (int p = 0; p < 4; ++p) {
        int u = t + p * 256;
        int r = u >> 4, c = u & 15;
        int swz = (c * 16) ^ ((r & 7) << 4);
        *(int4*)(lds + r * 256 + swz) = *(const int4*)(P1b + (size_t)r * NLQ + c * 8);
        *(int4*)(lds + 16384 + r * 256 + swz) = *(const int4*)(Qtb + (size_t)r * NLQ + c * 8);
        *(int4*)(lds + 32768 + r * 256 + swz) = *(const int4*)(Vtb + (size_t)r * NLQ + c * 8);
    }
    __syncthreads();
    f32x4a zero = {0.f, 0.f, 0.f, 0.f};
    f32x4a accA[4], accB[4];
#pragma unroll
    for (int nf = 0; nf < 4; ++nf) { accA[nf] = zero; accB[nf] = zero; }
#pragma unroll
    for (int ks = 0; ks < 4; ++ks) {
        int inner = ks * 64 + g * 16;
        bf16x8f a = *(const bf16x8f*)(lds + (16 * wv + r16) * 256 + (inner ^ ((r16 & 7) << 4)));
#pragma unroll
        for (int nf = 0; nf < 4; ++nf) {
            int ro = (16 * nf + r16) * 256 + (inner ^ ((r16 & 7) << 4));
            bf16x8f q = *(const bf16x8f*)(lds + 16384 + ro);
            accA[nf] = __builtin_amdgcn_mfma_f32_16x16x32_bf16(a, q, accA[nf], 0, 0, 0);
            bf16x8f vv = *(const bf16x8f*)(lds + 32768 + ro);
            accB[nf] = __builtin_amdgcn_mfma_f32_16x16x32_bf16(a, vv, accB[nf], 0, 0, 0);
        }
    }
#pragma unroll
    for (int nf = 0; nf < 4; ++nf) {
        int d = d0 + 16 * nf + r16;
#pragma unroll
        for (int reg = 0; reg < 4; ++reg) {
            int i = i0 + 16 * wv + 4 * g + reg;
            float cv = C[((size_t)b * NLC + i) * ND + d];
            float av = accA[nf][reg], bv = accB[nf][reg];
            float* orow = Out + ((size_t)b * NLC + i) * (4 * ND);
            orow[d] = cv;
            orow[ND + d] = av;
            orow[2 * ND + d] = cv * av;
            orow[3 * ND + d] = cv * bv;
        }
    }
}

// ---------------------------------------------------------------------------
extern "C" void kernel_launch(void* const* d_in, const int* in_sizes, int n_in,
                              void* d_out, int out_size, void* d_ws, size_t ws_size,
                              hipStream_t stream) {
    const float* C = (const float*)d_in[0];
    const float* Q = (const float*)d_in[1];
    const int* Cmask = (const int*)d_in[2];
    const int* Qmask = (const int*)d_in[3];
    const float* w = (const float*)d_in[4];
    float* out = (float*)d_out;

    // Early-stage scratch in d_out (all consumed before k_out overwrites it).
    char* ob = (char*)d_out;
    unsigned short* Cw3 = (unsigned short*)(ob + 0);          // 16,777,216
    unsigned short* Ct  = (unsigned short*)(ob + 16777216);   // 16,777,216
    unsigned short* Eb  = (unsigned short*)(ob + 33554432);   //  4,194,304
    unsigned short* Qb  = (unsigned short*)(ob + 37748736);   //  2,097,152
    float*          colm = (float*)(ob + 39845888);           //    131,072
    float*          colsv = (float*)(ob + 39976960);          //    131,072
    float*          pbuf = (float*)(ob + 40108032);           // 16,777,216

    // Final-stage scratch in ws (live while k_out writes d_out): ~8.3 MB.
    char* wb = (char*)d_ws;
    float* sc = (float*)(wb + 0);                       // 65,536
    float* sq = (float*)(wb + 65536);                   //  8,192
    unsigned short* P1 = (unsigned short*)(wb + 73728); // 4,194,304
    unsigned short* Qt = (unsigned short*)(wb + 4268032); // 2,097,152
    unsigned short* Vt = (unsigned short*)(wb + 6365184); // 2,097,152

    k_prep2<<<dim3(288), dim3(256), 0, stream>>>(C, Q, w, Cw3, Ct, Qb, Qt, sc, sq);
    k_S<<<dim3(16, 16), dim3(256), 0, stream>>>(Cw3, Qb, sc, sq, Qmask, Cmask, P1, Eb, colm, colsv);
    k_s2tc<<<dim3(8, 4, 16), dim3(256), 0, stream>>>(Eb, Ct, colm, colsv, pbuf);
    k_red<<<dim3(1024), dim3(256), 0, stream>>>(pbuf, Vt);
    k_out<<<dim3(8, 16, 16), dim3(256), 0, stream>>>(P1, Qt, Vt, C, out);
}

// Round 5
// 94.966 us; speedup vs baseline: 3.9131x; 1.0034x over previous
//
#include <hip/hip_runtime.h>
#include <hip/hip_bf16.h>
#include <math.h>

#define NB 16
#define NLC 1024
#define NLQ 128
#define ND 512
#define NEGV (-1.0e10f)

typedef __attribute__((ext_vector_type(8))) short bf16x8f;
typedef __attribute__((ext_vector_type(4))) float f32x4a;

__device__ inline unsigned short f2bf(float f) {
    unsigned u = __float_as_uint(f);
    unsigned r = (u + 0x7fffu + ((u >> 16) & 1u)) >> 16;
    return (unsigned short)r;
}

// ---------------------------------------------------------------------------
// k_prep2: single pass over C and Q producing
//   Cw3 bf16 [b][i][d] = C*w3 ; Ct bf16 [b][d][i] = C^T ; sc = C@w1
//   Qb  bf16 [b][j][d] = Q    ; Qt bf16 [b][d][j] = Q^T ; sq = Q@w2
// Blocks 0..255: C (b, 64-row tile). Blocks 256..287: Q.
__global__ __launch_bounds__(256) void k_prep2(const float* __restrict__ C,
                                               const float* __restrict__ Q,
                                               const float* __restrict__ w,
                                               unsigned short* __restrict__ Cw3,
                                               unsigned short* __restrict__ Ct,
                                               unsigned short* __restrict__ Qb,
                                               unsigned short* __restrict__ Qt,
                                               float* __restrict__ sc,
                                               float* __restrict__ sq) {
    __shared__ float T[64][65];
    int x = blockIdx.x, t = threadIdx.x;
    const float* src; const float* wdot; const float* wmul;
    unsigned short* rout; unsigned short* tout; float* sdst;
    int rows;
    if (x < 256) {
        int b = x >> 4, r0 = (x & 15) * 64;
        src = C + ((size_t)b * NLC + r0) * ND;
        wdot = w; wmul = w + 2 * ND;
        rout = Cw3 + ((size_t)b * NLC + r0) * ND;
        tout = Ct + (size_t)b * ND * NLC + r0;
        sdst = sc + b * NLC + r0;
        rows = NLC;
    } else {
        int x2 = x - 256;
        int b = x2 >> 1, r0 = (x2 & 1) * 64;
        src = Q + ((size_t)b * NLQ + r0) * ND;
        wdot = w + ND; wmul = nullptr;
        rout = Qb + ((size_t)b * NLQ + r0) * ND;
        tout = Qt + (size_t)b * ND * NLQ + r0;
        sdst = sq + b * NLQ + r0;
        rows = NLQ;
    }
    int r = t >> 2, s4 = (t & 3) * 16;
    float dacc = 0.f;
    for (int c = 0; c < 8; ++c) {
        int dbase = c * 64 + s4;
#pragma unroll
        for (int k = 0; k < 4; ++k) {
            float4 v = *(const float4*)&src[(size_t)r * ND + dbase + k * 4];
            float4 wd = *(const float4*)&wdot[dbase + k * 4];
            dacc += v.x * wd.x + v.y * wd.y + v.z * wd.z + v.w * wd.w;
            float4 vm;
            if (wmul) {
                float4 w3v = *(const float4*)&wmul[dbase + k * 4];
                vm = make_float4(v.x * w3v.x, v.y * w3v.y, v.z * w3v.z, v.w * w3v.w);
            } else {
                vm = v;
            }
            unsigned short o[4] = {f2bf(vm.x), f2bf(vm.y), f2bf(vm.z), f2bf(vm.w)};
            *(uint2*)&rout[(size_t)r * ND + dbase + k * 4] = *(uint2*)o;
            T[r][s4 + k * 4 + 0] = v.x;
            T[r][s4 + k * 4 + 1] = v.y;
            T[r][s4 + k * 4 + 2] = v.z;
            T[r][s4 + k * 4 + 3] = v.w;
        }
        __syncthreads();
        {   // transposed output: bf16(C) / bf16(Q)
            int dd = t >> 2, seg = (t & 3) * 16;
            unsigned short o16[16];
#pragma unroll
            for (int e = 0; e < 16; ++e) o16[e] = f2bf(T[seg + e][dd]);
            unsigned short* dp = tout + (size_t)(c * 64 + dd) * rows + seg;
            ((int4*)dp)[0] = ((int4*)o16)[0];
            ((int4*)dp)[1] = ((int4*)o16)[1];
        }
        __syncthreads();
    }
    dacc += __shfl_xor(dacc, 1, 64);
    dacc += __shfl_xor(dacc, 2, 64);
    if ((t & 3) == 0) sdst[r] = dacc;
}

// ---------------------------------------------------------------------------
// k_S: MFMA bf16 GEMM  S[i][j] = Cw3[i][:].Qb[j][:] + sc[i] + sq[j]  (K=512).
// Epilogue: row softmax (Qmask) -> P1 bf16 [b][i][j];
//           column partials (m,s per j over this 64-i tile, Cmask) -> colm/cols;
//           E bf16 [b][j][i] = exp(masked S - m_tile[j]) (LDS-transposed).
__global__ __launch_bounds__(256) void k_S(const unsigned short* __restrict__ Cw3,
                                           const unsigned short* __restrict__ Qb,
                                           const float* __restrict__ sc,
                                           const float* __restrict__ sq,
                                           const int* __restrict__ Qmask,
                                           const int* __restrict__ Cmask,
                                           unsigned short* __restrict__ P1,
                                           unsigned short* __restrict__ Eb,
                                           float* __restrict__ colm,
                                           float* __restrict__ cols) {
    __shared__ __align__(16) char lds[25088];
    int b = blockIdx.y, it = blockIdx.x, i0 = it * 64;
    int t = threadIdx.x, lane = t & 63, wv = t >> 6;
    int g = lane >> 4, r16 = lane & 15;
    const unsigned short* Asrc = Cw3 + ((size_t)b * NLC + i0) * ND;
    const unsigned short* Bsrc = Qb + (size_t)b * NLQ * ND;
    f32x4a zero = {0.f, 0.f, 0.f, 0.f};
    f32x4a acc[8];
#pragma unroll
    for (int nf = 0; nf < 8; ++nf) acc[nf] = zero;

    for (int kk = 0; kk < 8; ++kk) {
#pragma unroll
        for (int p = 0; p < 2; ++p) {  // A: 64 rows x 64 d
            int u = t + p * 256;
            int i = u >> 3, db = u & 7;
            int4 v = *(const int4*)(Asrc + (size_t)i * ND + kk * 64 + db * 8);
            *(int4*)(lds + i * 128 + ((db * 16) ^ ((i & 7) << 4))) = v;
        }
#pragma unroll
        for (int p = 0; p < 4; ++p) {  // B: 128 rows x 64 d
            int u = t + p * 256;
            int j = u >> 3, db = u & 7;
            int4 v = *(const int4*)(Bsrc + (size_t)j * ND + kk * 64 + db * 8);
            *(int4*)(lds + 8192 + j * 128 + ((db * 16) ^ ((j & 7) << 4))) = v;
        }
        __syncthreads();
#pragma unroll
        for (int ks = 0; ks < 2; ++ks) {
            int inner = ks * 64 + g * 16;
            bf16x8f a = *(const bf16x8f*)(lds + (16 * wv + r16) * 128 + (inner ^ ((r16 & 7) << 4)));
#pragma unroll
            for (int nf = 0; nf < 8; ++nf) {
                bf16x8f bq = *(const bf16x8f*)(lds + 8192 + (16 * nf + r16) * 128 + (inner ^ ((r16 & 7) << 4)));
                acc[nf] = __builtin_amdgcn_mfma_f32_16x16x32_bf16(a, bq, acc[nf], 0, 0, 0);
            }
        }
        __syncthreads();
    }

    // sv[nf][reg]: i = i0 + 16wv + 4g + reg ; j = 16nf + r16
    const float* scp = sc + b * NLC + i0;
    const float* sqp = sq + b * NLQ;
    const int* qm = Qmask + b * NLQ;
    const int* cmb = Cmask + b * NLC;
    float sv[8][4];
    float scr[4];
#pragma unroll
    for (int reg = 0; reg < 4; ++reg) scr[reg] = scp[16 * wv + 4 * g + reg];
    int qmv[8];
#pragma unroll
    for (int nf = 0; nf < 8; ++nf) {
        qmv[nf] = qm[16 * nf + r16];
        float sqv = sqp[16 * nf + r16];
#pragma unroll
        for (int reg = 0; reg < 4; ++reg) sv[nf][reg] = acc[nf][reg] + scr[reg] + sqv;
    }

    // ---- row softmax -> P1 ----
    unsigned short* P1p = P1 + ((size_t)b * NLC + i0) * NLQ;
#pragma unroll
    for (int reg = 0; reg < 4; ++reg) {
        float m = -INFINITY;
#pragma unroll
        for (int nf = 0; nf < 8; ++nf) m = fmaxf(m, qmv[nf] ? NEGV : sv[nf][reg]);
#pragma unroll
        for (int off = 8; off >= 1; off >>= 1) m = fmaxf(m, __shfl_xor(m, off, 64));
        float pv[8], s = 0.f;
#pragma unroll
        for (int nf = 0; nf < 8; ++nf) {
            pv[nf] = __expf((qmv[nf] ? NEGV : sv[nf][reg]) - m);
            s += pv[nf];
        }
#pragma unroll
        for (int off = 8; off >= 1; off >>= 1) s += __shfl_xor(s, off, 64);
        float rsi = 1.0f / s;
        int i = 16 * wv + 4 * g + reg;
#pragma unroll
        for (int nf = 0; nf < 8; ++nf)
            P1p[(size_t)i * NLQ + 16 * nf + r16] = f2bf(pv[nf] * rsi);
    }

    // ---- column partials over this tile's 64 i's ----
    int cmv[4];
#pragma unroll
    for (int reg = 0; reg < 4; ++reg) cmv[reg] = cmb[i0 + 16 * wv + 4 * g + reg];
    float vm2[8][4];
#pragma unroll
    for (int nf = 0; nf < 8; ++nf)
#pragma unroll
        for (int reg = 0; reg < 4; ++reg) vm2[nf][reg] = cmv[reg] ? NEGV : sv[nf][reg];

    float* cpm = (float*)(lds + 20480);
    float* cps = (float*)(lds + 22528);
    float* mtl = (float*)(lds + 24576);
    float cm8[8], cs8[8];
#pragma unroll
    for (int nf = 0; nf < 8; ++nf) {
        float m = vm2[nf][0];
#pragma unroll
        for (int reg = 1; reg < 4; ++reg) m = fmaxf(m, vm2[nf][reg]);
        float s = 0.f;
#pragma unroll
        for (int reg = 0; reg < 4; ++reg) s += __expf(vm2[nf][reg] - m);
#pragma unroll
        for (int off = 16; off <= 32; off <<= 1) {
            float mo = __shfl_xor(m, off, 64);
            float so = __shfl_xor(s, off, 64);
            float mn = fmaxf(m, mo);
            s = s * __expf(m - mn) + so * __expf(mo - mn);
            m = mn;
        }
        cm8[nf] = m; cs8[nf] = s;
    }
    if (g == 0) {
#pragma unroll
        for (int nf = 0; nf < 8; ++nf) {
            cpm[(wv * 8 + nf) * 16 + r16] = cm8[nf];
            cps[(wv * 8 + nf) * 16 + r16] = cs8[nf];
        }
    }
    __syncthreads();
    if (t < 128) {
        int j = t, nf = j >> 4, rr = j & 15;
        float M = cpm[(0 * 8 + nf) * 16 + rr];
        float S = cps[(0 * 8 + nf) * 16 + rr];
#pragma unroll
        for (int w2 = 1; w2 < 4; ++w2) {
            float mo = cpm[(w2 * 8 + nf) * 16 + rr];
            float so = cps[(w2 * 8 + nf) * 16 + rr];
            float mn = fmaxf(M, mo);
            S = S * __expf(M - mn) + so * __expf(mo - mn);
            M = mn;
        }
        colm[((size_t)b * 16 + it) * NLQ + j] = M;
        cols[((size_t)b * 16 + it) * NLQ + j] = S;
        mtl[j] = M;
    }
    __syncthreads();

    // ---- E bf16 [b][j][i] via LDS transpose ----
    unsigned short* ex = (unsigned short*)lds;  // [128][80]
#pragma unroll
    for (int nf = 0; nf < 8; ++nf) {
        float mj = mtl[16 * nf + r16];
        unsigned short e4[4];
#pragma unroll
        for (int reg = 0; reg < 4; ++reg) e4[reg] = f2bf(__expf(vm2[nf][reg] - mj));
        *(uint2*)&ex[(16 * nf + r16) * 80 + 16 * wv + 4 * g] = *(uint2*)e4;
    }
    __syncthreads();
    {
        int j = t >> 1, half = t & 1;
        unsigned short* Ep = Eb + ((size_t)b * NLQ + j) * NLC + i0 + half * 32;
#pragma unroll
        for (int c = 0; c < 4; ++c)
            *(int4*)&Ep[c * 8] = *(int4*)&ex[j * 80 + half * 32 + c * 8];
    }
}

// ---------------------------------------------------------------------------
// k_s2tc: pbuf[kc][b][d][j] = sum_{it in kc} f[it][j] * (E_it^T Ct_it)[j][d]
// f[it][j] = exp(colm[it][j]-M[j]) / S[j] computed in-block from colm/cols.
__global__ __launch_bounds__(256) void k_s2tc(const unsigned short* __restrict__ Eb,
                                              const unsigned short* __restrict__ Ct,
                                              const float* __restrict__ colm,
                                              const float* __restrict__ cols,
                                              float* __restrict__ pbuf) {
    __shared__ __align__(16) char lds[23552];  // f @0 (8K), A @8192 (10240), B @18432 (5120)
    int dt = blockIdx.x, kc = blockIdx.y, b = blockIdx.z;
    int t = threadIdx.x, lane = t & 63, wv = t >> 6, g = lane >> 4, r16 = lane & 15;
    float* fb = (float*)lds;

    if (t < 128) {  // global col stats + per-tile scale f
        int j = t;
        const float* cmp = colm + (size_t)b * 16 * NLQ + j;
        const float* csp = cols + (size_t)b * 16 * NLQ + j;
        float M = -INFINITY;
#pragma unroll
        for (int p = 0; p < 16; ++p) M = fmaxf(M, cmp[p * NLQ]);
        float S = 0.f;
#pragma unroll
        for (int p = 0; p < 16; ++p) S += csp[p * NLQ] * __expf(cmp[p * NLQ] - M);
        float inv = 1.0f / S;
#pragma unroll
        for (int p = 0; p < 16; ++p) fb[p * NLQ + j] = __expf(cmp[p * NLQ] - M) * inv;
    }
    __syncthreads();

    const unsigned short* Ebb = Eb + (size_t)b * NLQ * NLC;
    const unsigned short* Ctb = Ct + ((size_t)b * ND + dt * 64) * NLC;
    f32x4a zero = {0.f, 0.f, 0.f, 0.f};
    f32x4a acc2[2][4], V[2][4];
#pragma unroll
    for (int mf = 0; mf < 2; ++mf)
#pragma unroll
        for (int nf = 0; nf < 4; ++nf) { acc2[mf][nf] = zero; V[mf][nf] = zero; }

    for (int ib = kc * 256; ib < kc * 256 + 256; ib += 32) {
#pragma unroll
        for (int p = 0; p < 2; ++p) {  // A: E slice 128 j x 32 i
            int u = t + p * 256;
            int j = u >> 2, c8 = (u & 3) * 8;
            int4 v = *(const int4*)(Ebb + (size_t)j * NLC + ib + c8);
            *(int4*)(lds + 8192 + (j * 40 + c8) * 2) = v;
        }
        {   // B: Ct slice 64 d x 32 i
            int dd = t >> 2, c8 = (t & 3) * 8;
            int4 v = *(const int4*)(Ctb + (size_t)dd * NLC + ib + c8);
            *(int4*)(lds + 18432 + (dd * 40 + c8) * 2) = v;
        }
        __syncthreads();
#pragma unroll
        for (int mf = 0; mf < 2; ++mf) {
            bf16x8f a = *(const bf16x8f*)(lds + 8192 + ((32 * wv + 16 * mf + r16) * 40 + g * 8) * 2);
#pragma unroll
            for (int nf = 0; nf < 4; ++nf) {
                bf16x8f bb = *(const bf16x8f*)(lds + 18432 + ((16 * nf + r16) * 40 + g * 8) * 2);
                acc2[mf][nf] = __builtin_amdgcn_mfma_f32_16x16x32_bf16(a, bb, acc2[mf][nf], 0, 0, 0);
            }
        }
        __syncthreads();
        if (ib & 32) {  // finished an i-tile of 64: apply f and fold into V
            int itg = ib >> 6;
#pragma unroll
            for (int mf = 0; mf < 2; ++mf) {
                f32x4a f4 = *(const f32x4a*)(lds + (itg * NLQ + 32 * wv + 16 * mf + 4 * g) * 4);
#pragma unroll
                for (int nf = 0; nf < 4; ++nf) {
#pragma unroll
                    for (int reg = 0; reg < 4; ++reg)
                        V[mf][nf][reg] += f4[reg] * acc2[mf][nf][reg];
                    acc2[mf][nf] = zero;
                }
            }
        }
    }
    float* pb = pbuf + (((size_t)kc * NB + b) * ND + dt * 64) * NLQ;
#pragma unroll
    for (int mf = 0; mf < 2; ++mf)
#pragma unroll
        for (int nf = 0; nf < 4; ++nf) {
            float4 v;
            v.x = V[mf][nf][0]; v.y = V[mf][nf][1];
            v.z = V[mf][nf][2]; v.w = V[mf][nf][3];
            *(float4*)&pb[(size_t)(16 * nf + r16) * NLQ + 32 * wv + 16 * mf + 4 * g] = v;
        }
}

// ---------------------------------------------------------------------------
// k_red: Vt bf16 [b][d][j] = sum of 4 pbuf chunks.
__global__ __launch_bounds__(256) void k_red(const float* __restrict__ pbuf,
                                             unsigned short* __restrict__ Vt) {
    size_t u = (size_t)blockIdx.x * 256 + threadIdx.x;
    const size_t cs = (size_t)NB * ND * NLQ;
    float4 s = *(const float4*)&pbuf[u * 4];
#pragma unroll
    for (int c = 1; c < 4; ++c) {
        float4 v = *(const float4*)&pbuf[cs * c + u * 4];
        s.x += v.x; s.y += v.y; s.z += v.z; s.w += v.w;
    }
    unsigned short o[4] = {f2bf(s.x), f2bf(s.y), f2bf(s.z), f2bf(s.w)};
    *(uint2*)&Vt[u * 4] = *(uint2*)o;
}

// ---------------------------------------------------------------------------
// k_out: A = P1@Qt^T, Bv = P1@Vt^T (K=128, MFMA); out = [C, A, C*A, C*Bv].
// Epilogue: LDS round-trip of accumulators -> fully coalesced float4 IO.
__global__ __launch_bounds__(256) void k_out(const unsigned short* __restrict__ P1,
                                             const unsigned short* __restrict__ Qt,
                                             const unsigned short* __restrict__ Vt,
                                             const float* __restrict__ C,
                                             float* __restrict__ Out) {
    __shared__ __align__(16) char lds[49152];
    int dt = blockIdx.x, it = blockIdx.y, b = blockIdx.z;
    int i0 = it * 64, d0 = dt * 64;
    int t = threadIdx.x, lane = t & 63, wv = t >> 6, g = lane >> 4, r16 = lane & 15;
    const unsigned short* P1b = P1 + ((size_t)b * NLC + i0) * NLQ;
    const unsigned short* Qtb = Qt + ((size_t)b * ND + d0) * NLQ;
    const unsigned short* Vtb = Vt + ((size_t)b * ND + d0) * NLQ;
#pragma unroll
    for (int p = 0; p < 4; ++p) {
        int u = t + p * 256;
        int r = u >> 4, c = u & 15;
        int swz = (c * 16) ^ ((r & 7) << 4);
        *(int4*)(lds + r * 256 + swz) = *(const int4*)(P1b + (size_t)r * NLQ + c * 8);
        *(int4*)(lds + 16384 + r * 256 + swz) = *(const int4*)(Qtb + (size_t)r * NLQ + c * 8);
        *(int4*)(lds + 32768 + r * 256 + swz) = *(const int4*)(Vtb + (size_t)r * NLQ + c * 8);
    }
    __syncthreads();
    f32x4a zero = {0.f, 0.f, 0.f, 0.f};
    f32x4a accA[4], accB[4];
#pragma unroll
    for (int nf = 0; nf < 4; ++nf) { accA[nf] = zero; accB[nf] = zero; }
#pragma unroll
    for (int ks = 0; ks < 4; ++ks) {
        int inner = ks * 64 + g * 16;
        bf16x8f a = *(const bf16x8f*)(lds + (16 * wv + r16) * 256 + (inner ^ ((r16 & 7) << 4)));
#pragma unroll
        for (int nf = 0; nf < 4; ++nf) {
            int ro = (16 * nf + r16) * 256 + (inner ^ ((r16 & 7) << 4));
            bf16x8f q = *(const bf16x8f*)(lds + 16384 + ro);
            accA[nf] = __builtin_amdgcn_mfma_f32_16x16x32_bf16(a, q, accA[nf], 0, 0, 0);
            bf16x8f vv = *(const bf16x8f*)(lds + 32768 + ro);
            accB[nf] = __builtin_amdgcn_mfma_f32_16x16x32_bf16(a, vv, accB[nf], 0, 0, 0);
        }
    }
    __syncthreads();  // LDS staging done; reuse for accumulator transpose

    // Scatter fragments to LDS: At/Bt [64 i][68 pitch] f32.
    float* At = (float*)lds;               // 17,408 B
    float* Bt = (float*)(lds + 17408);     // 17,408 B (total 34,816 <= 49,152)
#pragma unroll
    for (int nf = 0; nf < 4; ++nf) {
        int dloc = 16 * nf + r16;
#pragma unroll
        for (int reg = 0; reg < 4; ++reg) {
            int iloc = 16 * wv + 4 * g + reg;
            At[iloc * 68 + dloc] = accA[nf][reg];
            Bt[iloc * 68 + dloc] = accB[nf][reg];
        }
    }
    __syncthreads();

    // Coalesced epilogue: 64 rows x 16 float4-cols = 1024 tasks, 4/thread.
    const float* Cb = C + ((size_t)b * NLC + i0) * ND + d0;
    float* Ob = Out + ((size_t)b * NLC + i0) * (4 * ND);
#pragma unroll
    for (int p = 0; p < 4; ++p) {
        int u = t + p * 256;
        int row = u >> 4, c4 = (u & 15) * 4;
        float4 cv = *(const float4*)&Cb[(size_t)row * ND + c4];
        float4 av = *(const float4*)&At[row * 68 + c4];
        float4 bv = *(const float4*)&Bt[row * 68 + c4];
        float4 ca, cb;
        ca.x = cv.x * av.x; ca.y = cv.y * av.y; ca.z = cv.z * av.z; ca.w = cv.w * av.w;
        cb.x = cv.x * bv.x; cb.y = cv.y * bv.y; cb.z = cv.z * bv.z; cb.w = cv.w * bv.w;
        float* orow = Ob + (size_t)row * (4 * ND);
        *(float4*)&orow[d0 + c4] = cv;
        *(float4*)&orow[ND + d0 + c4] = av;
        *(float4*)&orow[2 * ND + d0 + c4] = ca;
        *(float4*)&orow[3 * ND + d0 + c4] = cb;
    }
}

// ---------------------------------------------------------------------------
extern "C" void kernel_launch(void* const* d_in, const int* in_sizes, int n_in,
                              void* d_out, int out_size, void* d_ws, size_t ws_size,
                              hipStream_t stream) {
    const float* C = (const float*)d_in[0];
    const float* Q = (const float*)d_in[1];
    const int* Cmask = (const int*)d_in[2];
    const int* Qmask = (const int*)d_in[3];
    const float* w = (const float*)d_in[4];
    float* out = (float*)d_out;

    // Early-stage scratch in d_out (all consumed before k_out overwrites it).
    char* ob = (char*)d_out;
    unsigned short* Cw3 = (unsigned short*)(ob + 0);          // 16,777,216
    unsigned short* Ct  = (unsigned short*)(ob + 16777216);   // 16,777,216
    unsigned short* Eb  = (unsigned short*)(ob + 33554432);   //  4,194,304
    unsigned short* Qb  = (unsigned short*)(ob + 37748736);   //  2,097,152
    float*          colm = (float*)(ob + 39845888);           //    131,072
    float*          colsv = (float*)(ob + 39976960);          //    131,072
    float*          pbuf = (float*)(ob + 40108032);           // 16,777,216

    // Final-stage scratch in ws (live while k_out writes d_out): ~8.3 MB.
    char* wb = (char*)d_ws;
    float* sc = (float*)(wb + 0);                       // 65,536
    float* sq = (float*)(wb + 65536);                   //  8,192
    unsigned short* P1 = (unsigned short*)(wb + 73728); // 4,194,304
    unsigned short* Qt = (unsigned short*)(wb + 4268032); // 2,097,152
    unsigned short* Vt = (unsigned short*)(wb + 6365184); // 2,097,152

    k_prep2<<<dim3(288), dim3(256), 0, stream>>>(C, Q, w, Cw3, Ct, Qb, Qt, sc, sq);
    k_S<<<dim3(16, 16), dim3(256), 0, stream>>>(Cw3, Qb, sc, sq, Qmask, Cmask, P1, Eb, colm, colsv);
    k_s2tc<<<dim3(8, 4, 16), dim3(256), 0, stream>>>(Eb, Ct, colm, colsv, pbuf);
    k_red<<<dim3(1024), dim3(256), 0, stream>>>(pbuf, Vt);
    k_out<<<dim3(8, 16, 16), dim3(256), 0, stream>>>(P1, Qt, Vt, C, out);
}

// Round 6
// 80.209 us; speedup vs baseline: 4.6330x; 1.1840x over previous
//
#include <hip/hip_runtime.h>
#include <hip/hip_bf16.h>
#include <math.h>

#define NB 16
#define NLC 1024
#define NLQ 128
#define ND 512
#define NEGV (-1.0e10f)

typedef __attribute__((ext_vector_type(8))) short bf16x8f;
typedef __attribute__((ext_vector_type(4))) float f32x4a;

__device__ inline unsigned short f2bf(float f) {
    unsigned u = __float_as_uint(f);
    unsigned r = (u + 0x7fffu + ((u >> 16) & 1u)) >> 16;
    return (unsigned short)r;
}

// XCD-locality swizzle (m157 bijective form, nwg % 8 == 0): physical bid
// (round-robin over 8 XCDs) -> logical id such that each XCD gets one
// contiguous logical chunk. Logical layouts below are b-major, so each XCD
// owns 2 batches and their shared panels stay in its private L2.
__device__ inline int xcd_swz(int bid, int nwg) {
    int chunk = nwg >> 3;
    return (bid & 7) * chunk + (bid >> 3);
}

// ---------------------------------------------------------------------------
// k_prep2 (512 thr, 8 waves): single pass over C and Q producing
//   Cw3 bf16 [b][i][d] = C*w3 ; Ct bf16 [b][d][i] = C^T ; sc = C@w1
//   Qb  bf16 [b][j][d] = Q    ; Qt bf16 [b][d][j] = Q^T ; sq = Q@w2
// Blocks 0..255: C (b, 64-row tile). Blocks 256..287: Q.
__global__ __launch_bounds__(512) void k_prep2(const float* __restrict__ C,
                                               const float* __restrict__ Q,
                                               const float* __restrict__ w,
                                               unsigned short* __restrict__ Cw3,
                                               unsigned short* __restrict__ Ct,
                                               unsigned short* __restrict__ Qb,
                                               unsigned short* __restrict__ Qt,
                                               float* __restrict__ sc,
                                               float* __restrict__ sq) {
    __shared__ float T[64][65];
    int x = blockIdx.x, t = threadIdx.x;
    const float* src; const float* wdot; const float* wmul;
    unsigned short* rout; unsigned short* tout; float* sdst;
    int rows;
    if (x < 256) {
        int b = x >> 4, r0t = (x & 15) * 64;
        src = C + ((size_t)b * NLC + r0t) * ND;
        wdot = w; wmul = w + 2 * ND;
        rout = Cw3 + ((size_t)b * NLC + r0t) * ND;
        tout = Ct + (size_t)b * ND * NLC + r0t;
        sdst = sc + b * NLC + r0t;
        rows = NLC;
    } else {
        int x2 = x - 256;
        int b = x2 >> 1, r0t = (x2 & 1) * 64;
        src = Q + ((size_t)b * NLQ + r0t) * ND;
        wdot = w + ND; wmul = nullptr;
        rout = Qb + ((size_t)b * NLQ + r0t) * ND;
        tout = Qt + (size_t)b * ND * NLQ + r0t;
        sdst = sq + b * NLQ + r0t;
        rows = NLQ;
    }
    int r = t >> 3;          // 0..63 row in tile
    int s8 = (t & 7) * 8;    // col offset within 64-d chunk
    float dacc = 0.f;
    for (int c = 0; c < 8; ++c) {
        int dbase = c * 64 + s8;
        float4 v0 = *(const float4*)&src[(size_t)r * ND + dbase];
        float4 v1 = *(const float4*)&src[(size_t)r * ND + dbase + 4];
        float4 wd0 = *(const float4*)&wdot[dbase];
        float4 wd1 = *(const float4*)&wdot[dbase + 4];
        dacc += v0.x * wd0.x + v0.y * wd0.y + v0.z * wd0.z + v0.w * wd0.w;
        dacc += v1.x * wd1.x + v1.y * wd1.y + v1.z * wd1.z + v1.w * wd1.w;
        float f8[8] = {v0.x, v0.y, v0.z, v0.w, v1.x, v1.y, v1.z, v1.w};
        unsigned short o[8];
        if (wmul) {
            float4 w30 = *(const float4*)&wmul[dbase];
            float4 w31 = *(const float4*)&wmul[dbase + 4];
            float m8[8] = {w30.x, w30.y, w30.z, w30.w, w31.x, w31.y, w31.z, w31.w};
#pragma unroll
            for (int e = 0; e < 8; ++e) o[e] = f2bf(f8[e] * m8[e]);
        } else {
#pragma unroll
            for (int e = 0; e < 8; ++e) o[e] = f2bf(f8[e]);
        }
        *(int4*)&rout[(size_t)r * ND + dbase] = *(int4*)o;
#pragma unroll
        for (int e = 0; e < 8; ++e) T[r][s8 + e] = f8[e];
        __syncthreads();
        {   // transposed bf16 output: row d = c*64+dd, cols r0t+seg..+8
            int dd = t >> 3, seg = (t & 7) * 8;
            unsigned short o16[8];
#pragma unroll
            for (int e = 0; e < 8; ++e) o16[e] = f2bf(T[seg + e][dd]);
            *(int4*)&tout[(size_t)(c * 64 + dd) * rows + seg] = *(int4*)o16;
        }
        __syncthreads();
    }
    dacc += __shfl_xor(dacc, 1, 64);
    dacc += __shfl_xor(dacc, 2, 64);
    dacc += __shfl_xor(dacc, 4, 64);
    if ((t & 7) == 0) sdst[r] = dacc;
}

// ---------------------------------------------------------------------------
// k_S: MFMA bf16 GEMM  S[i][j] = Cw3[i][:].Qb[j][:] + sc[i] + sq[j]  (K=512).
// Epilogue: row softmax (Qmask) -> P1 bf16 [b][i][j];
//           column partials (m,s per j over this 64-i tile, Cmask) -> colm/cols;
//           E bf16 [b][j][i] = exp(masked S - m_tile[j]) (LDS-transposed).
// Grid: 256 blocks, b-major logical order under XCD swizzle.
__global__ __launch_bounds__(256) void k_S(const unsigned short* __restrict__ Cw3,
                                           const unsigned short* __restrict__ Qb,
                                           const float* __restrict__ sc,
                                           const float* __restrict__ sq,
                                           const int* __restrict__ Qmask,
                                           const int* __restrict__ Cmask,
                                           unsigned short* __restrict__ P1,
                                           unsigned short* __restrict__ Eb,
                                           float* __restrict__ colm,
                                           float* __restrict__ cols) {
    __shared__ __align__(16) char lds[25088];
    int lg = xcd_swz(blockIdx.x, 256);
    int b = lg >> 4, it = lg & 15, i0 = it * 64;
    int t = threadIdx.x, lane = t & 63, wv = t >> 6;
    int g = lane >> 4, r16 = lane & 15;
    const unsigned short* Asrc = Cw3 + ((size_t)b * NLC + i0) * ND;
    const unsigned short* Bsrc = Qb + (size_t)b * NLQ * ND;
    f32x4a zero = {0.f, 0.f, 0.f, 0.f};
    f32x4a acc[8];
#pragma unroll
    for (int nf = 0; nf < 8; ++nf) acc[nf] = zero;

    for (int kk = 0; kk < 8; ++kk) {
#pragma unroll
        for (int p = 0; p < 2; ++p) {  // A: 64 rows x 64 d
            int u = t + p * 256;
            int i = u >> 3, db = u & 7;
            int4 v = *(const int4*)(Asrc + (size_t)i * ND + kk * 64 + db * 8);
            *(int4*)(lds + i * 128 + ((db * 16) ^ ((i & 7) << 4))) = v;
        }
#pragma unroll
        for (int p = 0; p < 4; ++p) {  // B: 128 rows x 64 d
            int u = t + p * 256;
            int j = u >> 3, db = u & 7;
            int4 v = *(const int4*)(Bsrc + (size_t)j * ND + kk * 64 + db * 8);
            *(int4*)(lds + 8192 + j * 128 + ((db * 16) ^ ((j & 7) << 4))) = v;
        }
        __syncthreads();
#pragma unroll
        for (int ks = 0; ks < 2; ++ks) {
            int inner = ks * 64 + g * 16;
            bf16x8f a = *(const bf16x8f*)(lds + (16 * wv + r16) * 128 + (inner ^ ((r16 & 7) << 4)));
#pragma unroll
            for (int nf = 0; nf < 8; ++nf) {
                bf16x8f bq = *(const bf16x8f*)(lds + 8192 + (16 * nf + r16) * 128 + (inner ^ ((r16 & 7) << 4)));
                acc[nf] = __builtin_amdgcn_mfma_f32_16x16x32_bf16(a, bq, acc[nf], 0, 0, 0);
            }
        }
        __syncthreads();
    }

    // sv[nf][reg]: i = i0 + 16wv + 4g + reg ; j = 16nf + r16
    const float* scp = sc + b * NLC + i0;
    const float* sqp = sq + b * NLQ;
    const int* qm = Qmask + b * NLQ;
    const int* cmb = Cmask + b * NLC;
    float sv[8][4];
    float scr[4];
#pragma unroll
    for (int reg = 0; reg < 4; ++reg) scr[reg] = scp[16 * wv + 4 * g + reg];
    int qmv[8];
#pragma unroll
    for (int nf = 0; nf < 8; ++nf) {
        qmv[nf] = qm[16 * nf + r16];
        float sqv = sqp[16 * nf + r16];
#pragma unroll
        for (int reg = 0; reg < 4; ++reg) sv[nf][reg] = acc[nf][reg] + scr[reg] + sqv;
    }

    // ---- row softmax -> P1 ----
    unsigned short* P1p = P1 + ((size_t)b * NLC + i0) * NLQ;
#pragma unroll
    for (int reg = 0; reg < 4; ++reg) {
        float m = -INFINITY;
#pragma unroll
        for (int nf = 0; nf < 8; ++nf) m = fmaxf(m, qmv[nf] ? NEGV : sv[nf][reg]);
#pragma unroll
        for (int off = 8; off >= 1; off >>= 1) m = fmaxf(m, __shfl_xor(m, off, 64));
        float pv[8], s = 0.f;
#pragma unroll
        for (int nf = 0; nf < 8; ++nf) {
            pv[nf] = __expf((qmv[nf] ? NEGV : sv[nf][reg]) - m);
            s += pv[nf];
        }
#pragma unroll
        for (int off = 8; off >= 1; off >>= 1) s += __shfl_xor(s, off, 64);
        float rsi = 1.0f / s;
        int i = 16 * wv + 4 * g + reg;
#pragma unroll
        for (int nf = 0; nf < 8; ++nf)
            P1p[(size_t)i * NLQ + 16 * nf + r16] = f2bf(pv[nf] * rsi);
    }

    // ---- column partials over this tile's 64 i's ----
    int cmv[4];
#pragma unroll
    for (int reg = 0; reg < 4; ++reg) cmv[reg] = cmb[i0 + 16 * wv + 4 * g + reg];
    float vm2[8][4];
#pragma unroll
    for (int nf = 0; nf < 8; ++nf)
#pragma unroll
        for (int reg = 0; reg < 4; ++reg) vm2[nf][reg] = cmv[reg] ? NEGV : sv[nf][reg];

    float* cpm = (float*)(lds + 20480);
    float* cps = (float*)(lds + 22528);
    float* mtl = (float*)(lds + 24576);
    float cm8[8], cs8[8];
#pragma unroll
    for (int nf = 0; nf < 8; ++nf) {
        float m = vm2[nf][0];
#pragma unroll
        for (int reg = 1; reg < 4; ++reg) m = fmaxf(m, vm2[nf][reg]);
        float s = 0.f;
#pragma unroll
        for (int reg = 0; reg < 4; ++reg) s += __expf(vm2[nf][reg] - m);
#pragma unroll
        for (int off = 16; off <= 32; off <<= 1) {
            float mo = __shfl_xor(m, off, 64);
            float so = __shfl_xor(s, off, 64);
            float mn = fmaxf(m, mo);
            s = s * __expf(m - mn) + so * __expf(mo - mn);
            m = mn;
        }
        cm8[nf] = m; cs8[nf] = s;
    }
    if (g == 0) {
#pragma unroll
        for (int nf = 0; nf < 8; ++nf) {
            cpm[(wv * 8 + nf) * 16 + r16] = cm8[nf];
            cps[(wv * 8 + nf) * 16 + r16] = cs8[nf];
        }
    }
    __syncthreads();
    if (t < 128) {
        int j = t, nf = j >> 4, rr = j & 15;
        float M = cpm[(0 * 8 + nf) * 16 + rr];
        float S = cps[(0 * 8 + nf) * 16 + rr];
#pragma unroll
        for (int w2 = 1; w2 < 4; ++w2) {
            float mo = cpm[(w2 * 8 + nf) * 16 + rr];
            float so = cps[(w2 * 8 + nf) * 16 + rr];
            float mn = fmaxf(M, mo);
            S = S * __expf(M - mn) + so * __expf(mo - mn);
            M = mn;
        }
        colm[((size_t)b * 16 + it) * NLQ + j] = M;
        cols[((size_t)b * 16 + it) * NLQ + j] = S;
        mtl[j] = M;
    }
    __syncthreads();

    // ---- E bf16 [b][j][i] via LDS transpose ----
    unsigned short* ex = (unsigned short*)lds;  // [128][80]
#pragma unroll
    for (int nf = 0; nf < 8; ++nf) {
        float mj = mtl[16 * nf + r16];
        unsigned short e4[4];
#pragma unroll
        for (int reg = 0; reg < 4; ++reg) e4[reg] = f2bf(__expf(vm2[nf][reg] - mj));
        *(uint2*)&ex[(16 * nf + r16) * 80 + 16 * wv + 4 * g] = *(uint2*)e4;
    }
    __syncthreads();
    {
        int j = t >> 1, half = t & 1;
        unsigned short* Ep = Eb + ((size_t)b * NLQ + j) * NLC + i0 + half * 32;
#pragma unroll
        for (int c = 0; c < 4; ++c)
            *(int4*)&Ep[c * 8] = *(int4*)&ex[j * 80 + half * 32 + c * 8];
    }
}

// ---------------------------------------------------------------------------
// k_s2tc: pbuf[kc][b][d][j] = sum_{it in kc} f[it][j] * (E_it^T Ct_it)[j][d]
// f[it][j] = exp(colm[it][j]-M[j]) / S[j] computed in-block from colm/cols.
// Grid: 512 blocks, b-major logical order under XCD swizzle.
__global__ __launch_bounds__(256) void k_s2tc(const unsigned short* __restrict__ Eb,
                                              const unsigned short* __restrict__ Ct,
                                              const float* __restrict__ colm,
                                              const float* __restrict__ cols,
                                              float* __restrict__ pbuf) {
    __shared__ __align__(16) char lds[23552];  // f @0 (8K), A @8192 (10240), B @18432 (5120)
    int lg = xcd_swz(blockIdx.x, 512);
    int b = lg >> 5, kc = (lg >> 3) & 3, dt = lg & 7;
    int t = threadIdx.x, lane = t & 63, wv = t >> 6, g = lane >> 4, r16 = lane & 15;
    float* fb = (float*)lds;

    if (t < 128) {  // global col stats + per-tile scale f
        int j = t;
        const float* cmp = colm + (size_t)b * 16 * NLQ + j;
        const float* csp = cols + (size_t)b * 16 * NLQ + j;
        float M = -INFINITY;
#pragma unroll
        for (int p = 0; p < 16; ++p) M = fmaxf(M, cmp[p * NLQ]);
        float S = 0.f;
#pragma unroll
        for (int p = 0; p < 16; ++p) S += csp[p * NLQ] * __expf(cmp[p * NLQ] - M);
        float inv = 1.0f / S;
#pragma unroll
        for (int p = 0; p < 16; ++p) fb[p * NLQ + j] = __expf(cmp[p * NLQ] - M) * inv;
    }
    __syncthreads();

    const unsigned short* Ebb = Eb + (size_t)b * NLQ * NLC;
    const unsigned short* Ctb = Ct + ((size_t)b * ND + dt * 64) * NLC;
    f32x4a zero = {0.f, 0.f, 0.f, 0.f};
    f32x4a acc2[2][4], V[2][4];
#pragma unroll
    for (int mf = 0; mf < 2; ++mf)
#pragma unroll
        for (int nf = 0; nf < 4; ++nf) { acc2[mf][nf] = zero; V[mf][nf] = zero; }

    for (int ib = kc * 256; ib < kc * 256 + 256; ib += 32) {
#pragma unroll
        for (int p = 0; p < 2; ++p) {  // A: E slice 128 j x 32 i
            int u = t + p * 256;
            int j = u >> 2, c8 = (u & 3) * 8;
            int4 v = *(const int4*)(Ebb + (size_t)j * NLC + ib + c8);
            *(int4*)(lds + 8192 + (j * 40 + c8) * 2) = v;
        }
        {   // B: Ct slice 64 d x 32 i
            int dd = t >> 2, c8 = (t & 3) * 8;
            int4 v = *(const int4*)(Ctb + (size_t)dd * NLC + ib + c8);
            *(int4*)(lds + 18432 + (dd * 40 + c8) * 2) = v;
        }
        __syncthreads();
#pragma unroll
        for (int mf = 0; mf < 2; ++mf) {
            bf16x8f a = *(const bf16x8f*)(lds + 8192 + ((32 * wv + 16 * mf + r16) * 40 + g * 8) * 2);
#pragma unroll
            for (int nf = 0; nf < 4; ++nf) {
                bf16x8f bb = *(const bf16x8f*)(lds + 18432 + ((16 * nf + r16) * 40 + g * 8) * 2);
                acc2[mf][nf] = __builtin_amdgcn_mfma_f32_16x16x32_bf16(a, bb, acc2[mf][nf], 0, 0, 0);
            }
        }
        __syncthreads();
        if (ib & 32) {  // finished an i-tile of 64: apply f and fold into V
            int itg = ib >> 6;
#pragma unroll
            for (int mf = 0; mf < 2; ++mf) {
                f32x4a f4 = *(const f32x4a*)(lds + (itg * NLQ + 32 * wv + 16 * mf + 4 * g) * 4);
#pragma unroll
                for (int nf = 0; nf < 4; ++nf) {
#pragma unroll
                    for (int reg = 0; reg < 4; ++reg)
                        V[mf][nf][reg] += f4[reg] * acc2[mf][nf][reg];
                    acc2[mf][nf] = zero;
                }
            }
        }
    }
    float* pb = pbuf + (((size_t)kc * NB + b) * ND + dt * 64) * NLQ;
#pragma unroll
    for (int mf = 0; mf < 2; ++mf)
#pragma unroll
        for (int nf = 0; nf < 4; ++nf) {
            float4 v;
            v.x = V[mf][nf][0]; v.y = V[mf][nf][1];
            v.z = V[mf][nf][2]; v.w = V[mf][nf][3];
            *(float4*)&pb[(size_t)(16 * nf + r16) * NLQ + 32 * wv + 16 * mf + 4 * g] = v;
        }
}

// ---------------------------------------------------------------------------
// k_red: Vt bf16 [b][d][j] = sum of 4 pbuf chunks.
__global__ __launch_bounds__(256) void k_red(const float* __restrict__ pbuf,
                                             unsigned short* __restrict__ Vt) {
    size_t u = (size_t)blockIdx.x * 256 + threadIdx.x;
    const size_t cs = (size_t)NB * ND * NLQ;
    float4 s = *(const float4*)&pbuf[u * 4];
#pragma unroll
    for (int c = 1; c < 4; ++c) {
        float4 v = *(const float4*)&pbuf[cs * c + u * 4];
        s.x += v.x; s.y += v.y; s.z += v.z; s.w += v.w;
    }
    unsigned short o[4] = {f2bf(s.x), f2bf(s.y), f2bf(s.z), f2bf(s.w)};
    *(uint2*)&Vt[u * 4] = *(uint2*)o;
}

// ---------------------------------------------------------------------------
// k_out: A = P1@Qt^T, Bv = P1@Vt^T (K=128, MFMA); out = [C, A, C*A, C*Bv].
// Grid: 2048 blocks, b-major logical order under XCD swizzle.
__global__ __launch_bounds__(256) void k_out(const unsigned short* __restrict__ P1,
                                             const unsigned short* __restrict__ Qt,
                                             const unsigned short* __restrict__ Vt,
                                             const float* __restrict__ C,
                                             float* __restrict__ Out) {
    __shared__ __align__(16) char lds[49152];
    int lg = xcd_swz(blockIdx.x, 2048);
    int b = lg >> 7, rem = lg & 127, it = rem >> 3, dt = rem & 7;
    int i0 = it * 64, d0 = dt * 64;
    int t = threadIdx.x, lane = t & 63, wv = t >> 6, g = lane >> 4, r16 = lane & 15;
    const unsigned short* P1b = P1 + ((size_t)b * NLC + i0) * NLQ;
    const unsigned short* Qtb = Qt + ((size_t)b * ND + d0) * NLQ;
    const unsigned short* Vtb = Vt + ((size_t)b * ND + d0) * NLQ;
#pragma unroll
    for (int p = 0; p < 4; ++p) {
        int u = t + p * 256;
        int r = u >> 4, c = u & 15;
        int swz = (c * 16) ^ ((r & 7) << 4);
        *(int4*)(lds + r * 256 + swz) = *(const int4*)(P1b + (size_t)r * NLQ + c * 8);
        *(int4*)(lds + 16384 + r * 256 + swz) = *(const int4*)(Qtb + (size_t)r * NLQ + c * 8);
        *(int4*)(lds + 32768 + r * 256 + swz) = *(const int4*)(Vtb + (size_t)r * NLQ + c * 8);
    }
    __syncthreads();
    f32x4a zero = {0.f, 0.f, 0.f, 0.f};
    f32x4a accA[4], accB[4];
#pragma unroll
    for (int nf = 0; nf < 4; ++nf) { accA[nf] = zero; accB[nf] = zero; }
#pragma unroll
    for (int ks = 0; ks < 4; ++ks) {
        int inner = ks * 64 + g * 16;
        bf16x8f a = *(const bf16x8f*)(lds + (16 * wv + r16) * 256 + (inner ^ ((r16 & 7) << 4)));
#pragma unroll
        for (int nf = 0; nf < 4; ++nf) {
            int ro = (16 * nf + r16) * 256 + (inner ^ ((r16 & 7) << 4));
            bf16x8f q = *(const bf16x8f*)(lds + 16384 + ro);
            accA[nf] = __builtin_amdgcn_mfma_f32_16x16x32_bf16(a, q, accA[nf], 0, 0, 0);
            bf16x8f vv = *(const bf16x8f*)(lds + 32768 + ro);
            accB[nf] = __builtin_amdgcn_mfma_f32_16x16x32_bf16(a, vv, accB[nf], 0, 0, 0);
        }
    }
    __syncthreads();  // LDS staging done; reuse for accumulator transpose

    // Scatter fragments to LDS: At/Bt [64 i][68 pitch] f32.
    float* At = (float*)lds;               // 17,408 B
    float* Bt = (float*)(lds + 17408);     // 17,408 B (total 34,816 <= 49,152)
#pragma unroll
    for (int nf = 0; nf < 4; ++nf) {
        int dloc = 16 * nf + r16;
#pragma unroll
        for (int reg = 0; reg < 4; ++reg) {
            int iloc = 16 * wv + 4 * g + reg;
            At[iloc * 68 + dloc] = accA[nf][reg];
            Bt[iloc * 68 + dloc] = accB[nf][reg];
        }
    }
    __syncthreads();

    // Coalesced epilogue: 64 rows x 16 float4-cols = 1024 tasks, 4/thread.
    const float* Cb = C + ((size_t)b * NLC + i0) * ND + d0;
    float* Ob = Out + ((size_t)b * NLC + i0) * (4 * ND);
#pragma unroll
    for (int p = 0; p < 4; ++p) {
        int u = t + p * 256;
        int row = u >> 4, c4 = (u & 15) * 4;
        float4 cv = *(const float4*)&Cb[(size_t)row * ND + c4];
        float4 av = *(const float4*)&At[row * 68 + c4];
        float4 bv = *(const float4*)&Bt[row * 68 + c4];
        float4 ca, cb;
        ca.x = cv.x * av.x; ca.y = cv.y * av.y; ca.z = cv.z * av.z; ca.w = cv.w * av.w;
        cb.x = cv.x * bv.x; cb.y = cv.y * bv.y; cb.z = cv.z * bv.z; cb.w = cv.w * bv.w;
        float* orow = Ob + (size_t)row * (4 * ND);
        *(float4*)&orow[d0 + c4] = cv;
        *(float4*)&orow[ND + d0 + c4] = av;
        *(float4*)&orow[2 * ND + d0 + c4] = ca;
        *(float4*)&orow[3 * ND + d0 + c4] = cb;
    }
}

// ---------------------------------------------------------------------------
extern "C" void kernel_launch(void* const* d_in, const int* in_sizes, int n_in,
                              void* d_out, int out_size, void* d_ws, size_t ws_size,
                              hipStream_t stream) {
    const float* C = (const float*)d_in[0];
    const float* Q = (const float*)d_in[1];
    const int* Cmask = (const int*)d_in[2];
    const int* Qmask = (const int*)d_in[3];
    const float* w = (const float*)d_in[4];
    float* out = (float*)d_out;

    // Early-stage scratch in d_out (all consumed before k_out overwrites it).
    char* ob = (char*)d_out;
    unsigned short* Cw3 = (unsigned short*)(ob + 0);          // 16,777,216
    unsigned short* Ct  = (unsigned short*)(ob + 16777216);   // 16,777,216
    unsigned short* Eb  = (unsigned short*)(ob + 33554432);   //  4,194,304
    unsigned short* Qb  = (unsigned short*)(ob + 37748736);   //  2,097,152
    float*          colm = (float*)(ob + 39845888);           //    131,072
    float*          colsv = (float*)(ob + 39976960);          //    131,072
    float*          pbuf = (float*)(ob + 40108032);           // 16,777,216

    // Final-stage scratch in ws (live while k_out writes d_out): ~8.3 MB.
    char* wb = (char*)d_ws;
    float* sc = (float*)(wb + 0);                       // 65,536
    float* sq = (float*)(wb + 65536);                   //  8,192
    unsigned short* P1 = (unsigned short*)(wb + 73728); // 4,194,304
    unsigned short* Qt = (unsigned short*)(wb + 4268032); // 2,097,152
    unsigned short* Vt = (unsigned short*)(wb + 6365184); // 2,097,152

    k_prep2<<<dim3(288), dim3(512), 0, stream>>>(C, Q, w, Cw3, Ct, Qb, Qt, sc, sq);
    k_S<<<dim3(256), dim3(256), 0, stream>>>(Cw3, Qb, sc, sq, Qmask, Cmask, P1, Eb, colm, colsv);
    k_s2tc<<<dim3(512), dim3(256), 0, stream>>>(Eb, Ct, colm, colsv, pbuf);
    k_red<<<dim3(1024), dim3(256), 0, stream>>>(pbuf, Vt);
    k_out<<<dim3(2048), dim3(256), 0, stream>>>(P1, Qt, Vt, C, out);
}